// Round 1
// baseline (863.133 us; speedup 1.0000x reference)
//
#include <hip/hip_runtime.h>
#include <stdint.h>

typedef unsigned int u32;
typedef unsigned short u16;

#define NN   50000
#define NG   512
#define DIN  128
#define DH   256
#define DO_  128
#define BN_EPS 1e-5f

__device__ __forceinline__ float bf2f(u16 u) {
  union { u32 i; float f; } v; v.i = ((u32)u) << 16; return v.f;
}
__device__ __forceinline__ u16 f2bf(float f) {
  union { float f; u32 i; } v; v.f = f;
  return (u16)((v.i + 0x7FFFu + ((v.i >> 16) & 1u)) >> 16);
}
// Index loader robust to int32 or int64 storage (flag decided on device).
__device__ __forceinline__ int load_idx(const void* p, long long i, int is64) {
  return is64 ? (int)((const long long*)p)[i] : ((const int*)p)[i];
}

// Detect int64 indices: int32-view odd positions (high words) all zero.
__global__ void k_detect(const int* ei, int* flag) {
  if (threadIdx.x == 0 && blockIdx.x == 0) {
    int oddz = 0;
    for (int i = 0; i < 128; ++i) oddz += (ei[2 * i + 1] == 0) ? 1 : 0;
    *flag = (oddz == 128) ? 1 : 0;
  }
}

__global__ void k_count(const void* ei, int E, int* __restrict__ cnt, const int* flag) {
  int is64 = *flag;
  int e = blockIdx.x * blockDim.x + threadIdx.x;
  if (e < E) {
    int d = load_idx(ei, (long long)E + e, is64);
    atomicAdd(&cnt[d], 1);
  }
}

__global__ void k_dinv(const int* __restrict__ cnt, float* __restrict__ dinv) {
  int i = blockIdx.x * blockDim.x + threadIdx.x;
  if (i < NN) dinv[i] = rsqrtf((float)(cnt[i] + 1));
}

__global__ void k_scan1(const int* __restrict__ cnt, int* __restrict__ bsum) {
  __shared__ int s[256];
  int i = blockIdx.x * 256 + threadIdx.x;
  int v = (i < NN) ? (cnt[i] + 1) : 0;
  s[threadIdx.x] = v; __syncthreads();
  for (int st = 128; st > 0; st >>= 1) {
    if (threadIdx.x < st) s[threadIdx.x] += s[threadIdx.x + st];
    __syncthreads();
  }
  if (threadIdx.x == 0) bsum[blockIdx.x] = s[0];
}

__global__ void k_scan2(int* __restrict__ bsum, int nb) {
  __shared__ int s[256];
  int t = threadIdx.x;
  s[t] = (t < nb) ? bsum[t] : 0; __syncthreads();
  for (int off = 1; off < 256; off <<= 1) {
    int x = s[t];
    int y = (t >= off) ? s[t - off] : 0;
    __syncthreads();
    s[t] = x + y; __syncthreads();
  }
  if (t < nb) bsum[t] = (t == 0) ? 0 : s[t - 1];
}

__global__ void k_scan3(const int* __restrict__ cnt, const int* __restrict__ bbase,
                        int* __restrict__ offs) {
  __shared__ int s[256];
  int t = threadIdx.x;
  int i = blockIdx.x * 256 + t;
  int v = (i < NN) ? (cnt[i] + 1) : 0;
  s[t] = v; __syncthreads();
  for (int off = 1; off < 256; off <<= 1) {
    int x = s[t];
    int y = (t >= off) ? s[t - off] : 0;
    __syncthreads();
    s[t] = x + y; __syncthreads();
  }
  if (i < NN) offs[i] = bbase[blockIdx.x] + s[t] - v;  // exclusive
}

__global__ void k_fill(const void* ei, int E, const float* __restrict__ dinv,
                       const int* __restrict__ offs, int* __restrict__ cursor,
                       int* __restrict__ csr_s, float* __restrict__ csr_w, const int* flag) {
  int is64 = *flag;
  int e = blockIdx.x * blockDim.x + threadIdx.x;
  if (e >= E) return;
  int s = load_idx(ei, e, is64);
  int d = load_idx(ei, (long long)E + e, is64);
  int pos = atomicAdd(&cursor[d], 1);
  int idx = offs[d] + pos;
  csr_s[idx] = s;
  csr_w[idx] = dinv[s] * dinv[d];
}

__global__ void k_self(const int* __restrict__ cnt, const float* __restrict__ dinv,
                       const int* __restrict__ offs, int* __restrict__ csr_s,
                       float* __restrict__ csr_w) {
  int i = blockIdx.x * blockDim.x + threadIdx.x;
  if (i >= NN) return;
  int idx = offs[i] + cnt[i];
  csr_s[idx] = i;
  float di = dinv[i];
  csr_w[idx] = di * di;
}

__global__ void k_cast(const float* __restrict__ x, u16* __restrict__ y, int n) {
  int i = (blockIdx.x * blockDim.x + threadIdx.x) * 4;
  if (i + 3 < n) {
    float4 v = *(const float4*)(x + i);
    ushort4 o;
    o.x = f2bf(v.x); o.y = f2bf(v.y); o.z = f2bf(v.z); o.w = f2bf(v.w);
    *(ushort4*)(y + i) = o;
  }
}

// One wave per node: gather-weighted sum of bf16 rows, f32 accumulate.
template <int D>
__global__ __launch_bounds__(256) void k_agg(const u16* __restrict__ in,
    const int* __restrict__ offs, const int* __restrict__ cnt,
    const int* __restrict__ csr_s, const float* __restrict__ csr_w,
    float* __restrict__ out) {
  int node = (blockIdx.x * 256 + threadIdx.x) >> 6;
  int lane = threadIdx.x & 63;
  if (node >= NN) return;
  int beg = offs[node];
  int end = beg + cnt[node] + 1;
  if (D == 128) {
    float a0 = 0.f, a1 = 0.f;
    for (int e = beg; e < end; ++e) {
      int s = csr_s[e];
      float w = csr_w[e];
      u32 p = *(const u32*)(in + (size_t)s * 128 + lane * 2);
      a0 += w * bf2f((u16)(p & 0xFFFFu));
      a1 += w * bf2f((u16)(p >> 16));
    }
    out[(size_t)node * 128 + lane * 2 + 0] = a0;
    out[(size_t)node * 128 + lane * 2 + 1] = a1;
  } else {
    float a0 = 0.f, a1 = 0.f, a2 = 0.f, a3 = 0.f;
    for (int e = beg; e < end; ++e) {
      int s = csr_s[e];
      float w = csr_w[e];
      uint2 p = *(const uint2*)(in + (size_t)s * 256 + lane * 4);
      a0 += w * bf2f((u16)(p.x & 0xFFFFu));
      a1 += w * bf2f((u16)(p.x >> 16));
      a2 += w * bf2f((u16)(p.y & 0xFFFFu));
      a3 += w * bf2f((u16)(p.y >> 16));
    }
    *(float4*)(out + (size_t)node * 256 + lane * 4) = make_float4(a0, a1, a2, a3);
  }
}

// f32 GEMM: C[M,256] = A[M,K] @ W[K,256] + bias, bf16 output.
__global__ __launch_bounds__(256) void k_gemm(const float* __restrict__ A,
    const float* __restrict__ W, const float* __restrict__ bias,
    u16* __restrict__ out, int M, int K) {
  __shared__ float As[16][68];
  __shared__ float Ws[16][68];
  int tid = threadIdx.x;
  int tx = tid & 15, ty = tid >> 4;
  int rowBase = blockIdx.x * 64;
  int colBase = blockIdx.y * 64;
  float c[4][4] = {};
  for (int k0 = 0; k0 < K; k0 += 16) {
    {
      int m = tid >> 2, kq = tid & 3;
      int row = rowBase + m;
      float4 v = make_float4(0.f, 0.f, 0.f, 0.f);
      if (row < M) v = *(const float4*)(A + (size_t)row * K + k0 + kq * 4);
      As[kq * 4 + 0][m] = v.x; As[kq * 4 + 1][m] = v.y;
      As[kq * 4 + 2][m] = v.z; As[kq * 4 + 3][m] = v.w;
      int k = tid >> 4, nq = tid & 15;
      float4 wv = *(const float4*)(W + (size_t)(k0 + k) * 256 + colBase + nq * 4);
      Ws[k][nq * 4 + 0] = wv.x; Ws[k][nq * 4 + 1] = wv.y;
      Ws[k][nq * 4 + 2] = wv.z; Ws[k][nq * 4 + 3] = wv.w;
    }
    __syncthreads();
#pragma unroll
    for (int kk = 0; kk < 16; ++kk) {
      float a[4], b[4];
#pragma unroll
      for (int i = 0; i < 4; ++i) a[i] = As[kk][ty * 4 + i];
#pragma unroll
      for (int j = 0; j < 4; ++j) b[j] = Ws[kk][tx * 4 + j];
#pragma unroll
      for (int i = 0; i < 4; ++i)
#pragma unroll
        for (int j = 0; j < 4; ++j) c[i][j] += a[i] * b[j];
    }
    __syncthreads();
  }
#pragma unroll
  for (int i = 0; i < 4; ++i) {
    int row = rowBase + ty * 4 + i;
    if (row >= M) continue;
#pragma unroll
    for (int j = 0; j < 4; ++j) {
      int col = colBase + tx * 4 + j;
      out[(size_t)row * 256 + col] = f2bf(c[i][j] + bias[col]);
    }
  }
}

__global__ void k_stats(const u16* __restrict__ h, float* __restrict__ sum,
                        float* __restrict__ sumsq) {
  int c = threadIdx.x;
  float s = 0.f, q = 0.f;
  for (int r = blockIdx.x; r < NN; r += gridDim.x) {
    float v = bf2f(h[(size_t)r * 256 + c]);
    s += v; q += v * v;
  }
  atomicAdd(&sum[c], s);
  atomicAdd(&sumsq[c], q);
}

__global__ void k_scale(const float* __restrict__ sum, const float* __restrict__ sumsq,
                        const float* __restrict__ g, const float* __restrict__ be,
                        float* __restrict__ scale, float* __restrict__ shift) {
  int c = threadIdx.x;
  float mean = sum[c] / (float)NN;
  float var = sumsq[c] / (float)NN - mean * mean;
  float sc = g[c] * rsqrtf(var + BN_EPS);
  scale[c] = sc;
  shift[c] = be[c] - mean * sc;
}

__global__ void k_normcast(const u16* __restrict__ h, const float* __restrict__ scale,
                           const float* __restrict__ shift, u16* __restrict__ y) {
  int i = (blockIdx.x * blockDim.x + threadIdx.x) * 4;
  if (i >= NN * 256) return;
  int c = i & 255;
  ushort4 v = *(const ushort4*)(h + i);
  ushort4 o;
  o.x = f2bf(fmaxf(bf2f(v.x) * scale[c + 0] + shift[c + 0], 0.f));
  o.y = f2bf(fmaxf(bf2f(v.y) * scale[c + 1] + shift[c + 1], 0.f));
  o.z = f2bf(fmaxf(bf2f(v.z) * scale[c + 2] + shift[c + 2], 0.f));
  o.w = f2bf(fmaxf(bf2f(v.w) * scale[c + 3] + shift[c + 3], 0.f));
  *(ushort4*)(y + i) = o;
}

__global__ void k_cnt(const void* batch, int* __restrict__ Gcnt, const int* flag) {
  int is64 = *flag;
  int i = blockIdx.x * blockDim.x + threadIdx.x;
  if (i < NN) atomicAdd(&Gcnt[load_idx(batch, i, is64)], 1);
}

// batch_ids sorted: 64 nodes/block, per-thread local accumulation per column.
__global__ __launch_bounds__(256) void k_pool(const u16* __restrict__ h,
    const float* __restrict__ scale, const float* __restrict__ shift,
    const void* batch, float* __restrict__ Gsum, const int* flag) {
  int is64 = *flag;
  int c = threadIdx.x;
  int nodeBase = blockIdx.x * 64;
  float sc = scale[c], sh = shift[c];
  float local = 0.f;
  int cur = -1;
  int nmax = min(64, NN - nodeBase);
  for (int r = 0; r < nmax; ++r) {
    int node = nodeBase + r;
    int b = load_idx(batch, node, is64);
    if (b != cur) {
      if (cur >= 0) atomicAdd(&Gsum[(size_t)cur * 256 + c], local);
      cur = b; local = 0.f;
    }
    float v = bf2f(h[(size_t)node * 256 + c]) * sc + sh;
    local += fmaxf(v, 0.f);
  }
  if (cur >= 0) atomicAdd(&Gsum[(size_t)cur * 256 + c], local);
}

__global__ __launch_bounds__(128) void k_fc(const float* __restrict__ Gsum,
    const int* __restrict__ Gcnt, const float* __restrict__ Wfc,
    const float* __restrict__ bfc, float* __restrict__ out) {
  int g = blockIdx.x, j = threadIdx.x;
  float inv = 1.0f / fmaxf((float)Gcnt[g], 1.0f);
  float acc = 0.f;
#pragma unroll 4
  for (int c = 0; c < 256; ++c) acc += Gsum[(size_t)g * 256 + c] * Wfc[c * 128 + j];
  out[(size_t)g * 128 + j] = acc * inv + bfc[j];
}

extern "C" void kernel_launch(void* const* d_in, const int* in_sizes, int n_in,
                              void* d_out, int out_size, void* d_ws, size_t ws_size,
                              hipStream_t stream) {
  const float* V   = (const float*)d_in[0];
  const void*  EI  = d_in[1];
  const void*  BAT = d_in[2];
  const float* W1  = (const float*)d_in[3];
  const float* b1  = (const float*)d_in[4];
  const float* g1  = (const float*)d_in[5];
  const float* be1 = (const float*)d_in[6];
  const float* W2  = (const float*)d_in[7];
  const float* b2  = (const float*)d_in[8];
  const float* g2  = (const float*)d_in[9];
  const float* be2 = (const float*)d_in[10];
  const float* Wfc = (const float*)d_in[11];
  const float* bfc = (const float*)d_in[12];
  float* out = (float*)d_out;
  const int E  = in_sizes[1] / 2;
  const int NE = E + NN;

  char* w = (char*)d_ws;
  size_t o = 0;
  auto alloc = [&](size_t bytes) -> char* {
    char* r = w + o;
    o = (o + bytes + 255) & ~(size_t)255;
    return r;
  };
  int*   flag   = (int*)alloc(4);
  int*   deg    = (int*)alloc((size_t)NN * 4);
  int*   cursor = (int*)alloc((size_t)NN * 4);
  int*   offs   = (int*)alloc((size_t)NN * 4);
  int*   bsum   = (int*)alloc(256 * 4);
  int*   csr_s  = (int*)alloc((size_t)NE * 4);
  float* csr_w  = (float*)alloc((size_t)NE * 4);
  float* dinv   = (float*)alloc((size_t)NN * 4);
  float* stats  = (float*)alloc(8 * 256 * 4);
  float *sums1 = stats, *sumsq1 = stats + 256, *sums2 = stats + 512, *sumsq2 = stats + 768;
  float *scale1 = stats + 1024, *shift1 = stats + 1280, *scale2 = stats + 1536, *shift2 = stats + 1792;
  float* Gsum   = (float*)alloc((size_t)NG * DH * 4);
  int*   Gcnt   = (int*)alloc(NG * 4);
  u16*   Vb     = (u16*)alloc((size_t)NN * DIN * 2);
  float* aggV   = (float*)alloc((size_t)NN * DIN * 4);  // 25.6 MB
  u16*   h1b    = (u16*)alloc((size_t)NN * DH * 2);     // adjacent: alias below spans both
  float* agg2f  = (float*)aggV;                         // 51.2 MB alias over aggV+h1b
  u16*   h1n    = (u16*)alloc((size_t)NN * DH * 2);
  u16*   h2b    = (u16*)alloc((size_t)NN * DH * 2);
  (void)n_in; (void)out_size; (void)ws_size;

  hipMemsetAsync(deg, 0, (size_t)NN * 4, stream);
  hipMemsetAsync(cursor, 0, (size_t)NN * 4, stream);
  hipMemsetAsync(stats, 0, 4 * 256 * 4, stream);
  hipMemsetAsync(Gsum, 0, (size_t)NG * DH * 4 + NG * 4, stream);

  const int gE = (E + 255) / 256;
  const int gN = (NN + 255) / 256;

  k_detect<<<1, 64, 0, stream>>>((const int*)EI, flag);
  k_count<<<gE, 256, 0, stream>>>(EI, E, deg, flag);
  k_dinv<<<gN, 256, 0, stream>>>(deg, dinv);
  k_scan1<<<gN, 256, 0, stream>>>(deg, bsum);
  k_scan2<<<1, 256, 0, stream>>>(bsum, gN);
  k_scan3<<<gN, 256, 0, stream>>>(deg, bsum, offs);
  k_fill<<<gE, 256, 0, stream>>>(EI, E, dinv, offs, cursor, csr_s, csr_w, flag);
  k_self<<<gN, 256, 0, stream>>>(deg, dinv, offs, csr_s, csr_w);
  k_cast<<<(NN * DIN / 4 + 255) / 256, 256, 0, stream>>>(V, Vb, NN * DIN);
  k_agg<128><<<(NN + 3) / 4, 256, 0, stream>>>(Vb, offs, deg, csr_s, csr_w, aggV);
  k_gemm<<<dim3((NN + 63) / 64, 4), 256, 0, stream>>>(aggV, W1, b1, h1b, NN, DIN);
  k_stats<<<512, 256, 0, stream>>>(h1b, sums1, sumsq1);
  k_scale<<<1, 256, 0, stream>>>(sums1, sumsq1, g1, be1, scale1, shift1);
  k_normcast<<<(NN * DH / 4 + 255) / 256, 256, 0, stream>>>(h1b, scale1, shift1, h1n);
  k_agg<256><<<(NN + 3) / 4, 256, 0, stream>>>(h1n, offs, deg, csr_s, csr_w, agg2f);
  k_gemm<<<dim3((NN + 63) / 64, 4), 256, 0, stream>>>(agg2f, W2, b2, h2b, NN, DH);
  k_stats<<<512, 256, 0, stream>>>(h2b, sums2, sumsq2);
  k_scale<<<1, 256, 0, stream>>>(sums2, sumsq2, g2, be2, scale2, shift2);
  k_cnt<<<gN, 256, 0, stream>>>(BAT, Gcnt, flag);
  k_pool<<<(NN + 63) / 64, 256, 0, stream>>>(h2b, scale2, shift2, BAT, Gsum, flag);
  k_fc<<<NG, 128, 0, stream>>>(Gsum, Gcnt, Wfc, bfc, out);
}

// Round 2
// 630.276 us; speedup vs baseline: 1.3695x; 1.3695x over previous
//
#include <hip/hip_runtime.h>
#include <stdint.h>

typedef unsigned int u32;
typedef unsigned short u16;
typedef __attribute__((ext_vector_type(8))) short short8;
typedef __attribute__((ext_vector_type(4))) float f32x4;

#define NN   50000
#define NPAD 50048
#define NG   512
#define DIN  128
#define DH   256
#define BN_EPS 1e-5f

__device__ __forceinline__ float bf2f(u16 u) {
  union { u32 i; float f; } v; v.i = ((u32)u) << 16; return v.f;
}
__device__ __forceinline__ u16 f2bf(float f) {
  union { float f; u32 i; } v; v.f = f;
  return (u16)((v.i + 0x7FFFu + ((v.i >> 16) & 1u)) >> 16);
}
__device__ __forceinline__ int load_idx(const void* p, long long i, int is64) {
  return is64 ? (int)((const long long*)p)[i] : ((const int*)p)[i];
}

__global__ void k_detect(const int* ei, int* flag) {
  if (threadIdx.x == 0 && blockIdx.x == 0) {
    int oddz = 0;
    for (int i = 0; i < 128; ++i) oddz += (ei[2 * i + 1] == 0) ? 1 : 0;
    *flag = (oddz == 128) ? 1 : 0;
  }
}

__global__ void k_count(const void* ei, int E, int* __restrict__ cnt, const int* flag) {
  int is64 = *flag;
  int e = blockIdx.x * blockDim.x + threadIdx.x;
  if (e < E) {
    int d = load_idx(ei, (long long)E + e, is64);
    atomicAdd(&cnt[d], 1);
  }
}

__global__ void k_dinv(const int* __restrict__ cnt, float* __restrict__ dinv) {
  int i = blockIdx.x * blockDim.x + threadIdx.x;
  if (i < NN) dinv[i] = rsqrtf((float)(cnt[i] + 1));
}

__global__ void k_scan1(const int* __restrict__ cnt, int* __restrict__ bsum) {
  __shared__ int s[256];
  int i = blockIdx.x * 256 + threadIdx.x;
  int v = (i < NN) ? (cnt[i] + 1) : 0;
  s[threadIdx.x] = v; __syncthreads();
  for (int st = 128; st > 0; st >>= 1) {
    if (threadIdx.x < st) s[threadIdx.x] += s[threadIdx.x + st];
    __syncthreads();
  }
  if (threadIdx.x == 0) bsum[blockIdx.x] = s[0];
}

__global__ void k_scan2(int* __restrict__ bsum, int nb) {
  __shared__ int s[256];
  int t = threadIdx.x;
  s[t] = (t < nb) ? bsum[t] : 0; __syncthreads();
  for (int off = 1; off < 256; off <<= 1) {
    int x = s[t];
    int y = (t >= off) ? s[t - off] : 0;
    __syncthreads();
    s[t] = x + y; __syncthreads();
  }
  if (t < nb) bsum[t] = (t == 0) ? 0 : s[t - 1];
}

__global__ void k_scan3(const int* __restrict__ cnt, const int* __restrict__ bbase,
                        int* __restrict__ offs) {
  __shared__ int s[256];
  int t = threadIdx.x;
  int i = blockIdx.x * 256 + t;
  int v = (i < NN) ? (cnt[i] + 1) : 0;
  s[t] = v; __syncthreads();
  for (int off = 1; off < 256; off <<= 1) {
    int x = s[t];
    int y = (t >= off) ? s[t - off] : 0;
    __syncthreads();
    s[t] = x + y; __syncthreads();
  }
  if (i < NN) offs[i] = bbase[blockIdx.x] + s[t] - v;
}

__global__ void k_fill(const void* ei, int E, const float* __restrict__ dinv,
                       const int* __restrict__ offs, int* __restrict__ cursor,
                       int* __restrict__ csr_s, float* __restrict__ csr_w, const int* flag) {
  int is64 = *flag;
  int e = blockIdx.x * blockDim.x + threadIdx.x;
  if (e >= E) return;
  int s = load_idx(ei, e, is64);
  int d = load_idx(ei, (long long)E + e, is64);
  int pos = atomicAdd(&cursor[d], 1);
  int idx = offs[d] + pos;
  csr_s[idx] = s;
  csr_w[idx] = dinv[s] * dinv[d];
}

__global__ void k_self(const int* __restrict__ cnt, const float* __restrict__ dinv,
                       const int* __restrict__ offs, int* __restrict__ csr_s,
                       float* __restrict__ csr_w) {
  int i = blockIdx.x * blockDim.x + threadIdx.x;
  if (i >= NN) return;
  int idx = offs[i] + cnt[i];
  csr_s[idx] = i;
  float di = dinv[i];
  csr_w[idx] = di * di;
}

__global__ void k_cast(const float* __restrict__ x, u16* __restrict__ y, int n) {
  int i = (blockIdx.x * blockDim.x + threadIdx.x) * 4;
  if (i + 3 < n) {
    float4 v = *(const float4*)(x + i);
    ushort4 o;
    o.x = f2bf(v.x); o.y = f2bf(v.y); o.z = f2bf(v.z); o.w = f2bf(v.w);
    *(ushort4*)(y + i) = o;
  }
}

// W [K][256] f32 -> Wt [256][K] bf16
__global__ void k_wt(const float* __restrict__ W, u16* __restrict__ Wt, int K) {
  int i = blockIdx.x * 256 + threadIdx.x;
  if (i < K * 256) {
    int k = i >> 8, c = i & 255;
    Wt[c * K + k] = f2bf(W[i]);
  }
}

// Vectorized gather-aggregate: 16 B/lane, multi-edge per wave, bf16 output.
// D=128: 4 edges/iter (16 lanes x 16B per row). D=256: 2 edges/iter.
template <int D>
__global__ __launch_bounds__(256) void k_agg(const u16* __restrict__ in,
    const int* __restrict__ offs, const int* __restrict__ cnt,
    const int* __restrict__ csr_s, const float* __restrict__ csr_w,
    u16* __restrict__ out) {
  int node = (blockIdx.x * 256 + threadIdx.x) >> 6;
  int lane = threadIdx.x & 63;
  if (node >= NN) return;
  int beg = offs[node];
  int end = beg + cnt[node] + 1;
  float acc[8] = {};
  if (D == 128) {
    int grp = lane >> 4, sub = lane & 15;
    for (int e = beg + grp; e < end; e += 4) {
      int s = csr_s[e];
      float w = csr_w[e];
      uint4 p = *(const uint4*)(in + (size_t)s * 128 + sub * 8);
      u32 pp[4] = {p.x, p.y, p.z, p.w};
#pragma unroll
      for (int j = 0; j < 4; ++j) {
        acc[2 * j + 0] += w * bf2f((u16)(pp[j] & 0xFFFFu));
        acc[2 * j + 1] += w * bf2f((u16)(pp[j] >> 16));
      }
    }
#pragma unroll
    for (int j = 0; j < 8; ++j) {
      acc[j] += __shfl_xor(acc[j], 16, 64);
      acc[j] += __shfl_xor(acc[j], 32, 64);
    }
    if (lane < 16) {
      ushort4 o0, o1;
      o0.x = f2bf(acc[0]); o0.y = f2bf(acc[1]); o0.z = f2bf(acc[2]); o0.w = f2bf(acc[3]);
      o1.x = f2bf(acc[4]); o1.y = f2bf(acc[5]); o1.z = f2bf(acc[6]); o1.w = f2bf(acc[7]);
      *(ushort4*)(out + (size_t)node * 128 + lane * 8 + 0) = o0;
      *(ushort4*)(out + (size_t)node * 128 + lane * 8 + 4) = o1;
    }
  } else {
    int grp = lane >> 5, sub = lane & 31;
    for (int e = beg + grp; e < end; e += 2) {
      int s = csr_s[e];
      float w = csr_w[e];
      uint4 p = *(const uint4*)(in + (size_t)s * 256 + sub * 8);
      u32 pp[4] = {p.x, p.y, p.z, p.w};
#pragma unroll
      for (int j = 0; j < 4; ++j) {
        acc[2 * j + 0] += w * bf2f((u16)(pp[j] & 0xFFFFu));
        acc[2 * j + 1] += w * bf2f((u16)(pp[j] >> 16));
      }
    }
#pragma unroll
    for (int j = 0; j < 8; ++j) acc[j] += __shfl_xor(acc[j], 32, 64);
    if (lane < 32) {
      ushort4 o0, o1;
      o0.x = f2bf(acc[0]); o0.y = f2bf(acc[1]); o0.z = f2bf(acc[2]); o0.w = f2bf(acc[3]);
      o1.x = f2bf(acc[4]); o1.y = f2bf(acc[5]); o1.z = f2bf(acc[6]); o1.w = f2bf(acc[7]);
      *(ushort4*)(out + (size_t)node * 256 + lane * 8 + 0) = o0;
      *(ushort4*)(out + (size_t)node * 256 + lane * 8 + 4) = o1;
    }
  }
}

// bf16 MFMA GEMM: C[M,256] = A[M,K] @ B[K,256] + bias, A bf16 row-major,
// Bt = B^T bf16 [256][K]. 128x128 tile, BK=32, 4 waves of 64x64 each.
__global__ __launch_bounds__(256) void k_mgemm(const u16* __restrict__ A,
    const u16* __restrict__ Bt, const float* __restrict__ bias,
    u16* __restrict__ out, int M, int K) {
  __shared__ __align__(16) u16 As[128 * 32];
  __shared__ __align__(16) u16 Bs[128 * 32];
  int t = threadIdx.x;
  int l = t & 63;
  int w = t >> 6;
  int rowBase = blockIdx.x * 128;
  int colBase = blockIdx.y * 128;
  int wr = (w >> 1) * 64, wc = (w & 1) * 64;
  int rsel = l & 15, ksel = (l >> 4) * 8;

  f32x4 acc[4][4];
#pragma unroll
  for (int mi = 0; mi < 4; ++mi)
#pragma unroll
    for (int ni = 0; ni < 4; ++ni) acc[mi][ni] = (f32x4){0.f, 0.f, 0.f, 0.f};

  for (int k0 = 0; k0 < K; k0 += 32) {
#pragma unroll
    for (int c = 0; c < 2; ++c) {
      int idx = c * 256 + t;              // 0..511 -> 16B chunks
      int row = idx >> 2;
      int kq = idx & 3;
      const u16* ga = A + (size_t)(rowBase + row) * K + k0 + kq * 8;
      const u16* gb = Bt + (size_t)(colBase + row) * K + k0 + kq * 8;
      __builtin_amdgcn_global_load_lds(
          (const __attribute__((address_space(1))) void*)ga,
          (__attribute__((address_space(3))) void*)(&As[idx * 8]), 16, 0, 0);
      __builtin_amdgcn_global_load_lds(
          (const __attribute__((address_space(1))) void*)gb,
          (__attribute__((address_space(3))) void*)(&Bs[idx * 8]), 16, 0, 0);
    }
    __syncthreads();
    short8 a[4], b[4];
#pragma unroll
    for (int mi = 0; mi < 4; ++mi)
      a[mi] = *(const short8*)(&As[(wr + mi * 16 + rsel) * 32 + ksel]);
#pragma unroll
    for (int ni = 0; ni < 4; ++ni)
      b[ni] = *(const short8*)(&Bs[(wc + ni * 16 + rsel) * 32 + ksel]);
#pragma unroll
    for (int mi = 0; mi < 4; ++mi)
#pragma unroll
      for (int ni = 0; ni < 4; ++ni)
        acc[mi][ni] = __builtin_amdgcn_mfma_f32_16x16x32_bf16(a[mi], b[ni], acc[mi][ni], 0, 0, 0);
    __syncthreads();
  }

#pragma unroll
  for (int mi = 0; mi < 4; ++mi) {
#pragma unroll
    for (int r = 0; r < 4; ++r) {
      int row = rowBase + wr + mi * 16 + (l >> 4) * 4 + r;
      if (row >= M) continue;
#pragma unroll
      for (int ni = 0; ni < 4; ++ni) {
        int col = colBase + wc + ni * 16 + (l & 15);
        out[(size_t)row * 256 + col] = f2bf(acc[mi][ni][r] + bias[col]);
      }
    }
  }
}

__global__ void k_stats(const u16* __restrict__ h, float* __restrict__ sum,
                        float* __restrict__ sumsq) {
  int c = threadIdx.x;
  float s = 0.f, q = 0.f;
  for (int r = blockIdx.x; r < NN; r += gridDim.x) {
    float v = bf2f(h[(size_t)r * 256 + c]);
    s += v; q += v * v;
  }
  atomicAdd(&sum[c], s);
  atomicAdd(&sumsq[c], q);
}

__global__ void k_scale(const float* __restrict__ sum, const float* __restrict__ sumsq,
                        const float* __restrict__ g, const float* __restrict__ be,
                        float* __restrict__ scale, float* __restrict__ shift) {
  int c = threadIdx.x;
  float mean = sum[c] / (float)NN;
  float var = sumsq[c] / (float)NN - mean * mean;
  float sc = g[c] * rsqrtf(var + BN_EPS);
  scale[c] = sc;
  shift[c] = be[c] - mean * sc;
}

__global__ void k_normcast(const u16* __restrict__ h, const float* __restrict__ scale,
                           const float* __restrict__ shift, u16* __restrict__ y) {
  int i = (blockIdx.x * blockDim.x + threadIdx.x) * 4;
  if (i >= NN * 256) return;
  int c = i & 255;
  ushort4 v = *(const ushort4*)(h + i);
  ushort4 o;
  o.x = f2bf(fmaxf(bf2f(v.x) * scale[c + 0] + shift[c + 0], 0.f));
  o.y = f2bf(fmaxf(bf2f(v.y) * scale[c + 1] + shift[c + 1], 0.f));
  o.z = f2bf(fmaxf(bf2f(v.z) * scale[c + 2] + shift[c + 2], 0.f));
  o.w = f2bf(fmaxf(bf2f(v.w) * scale[c + 3] + shift[c + 3], 0.f));
  *(ushort4*)(y + i) = o;
}

__global__ void k_cnt(const void* batch, int* __restrict__ Gcnt, const int* flag) {
  int is64 = *flag;
  int i = blockIdx.x * blockDim.x + threadIdx.x;
  if (i < NN) atomicAdd(&Gcnt[load_idx(batch, i, is64)], 1);
}

__global__ __launch_bounds__(256) void k_pool(const u16* __restrict__ h,
    const float* __restrict__ scale, const float* __restrict__ shift,
    const void* batch, float* __restrict__ Gsum, const int* flag) {
  int is64 = *flag;
  int c = threadIdx.x;
  int nodeBase = blockIdx.x * 64;
  float sc = scale[c], sh = shift[c];
  float local = 0.f;
  int cur = -1;
  int nmax = min(64, NN - nodeBase);
  for (int r = 0; r < nmax; ++r) {
    int node = nodeBase + r;
    int b = load_idx(batch, node, is64);
    if (b != cur) {
      if (cur >= 0) atomicAdd(&Gsum[(size_t)cur * 256 + c], local);
      cur = b; local = 0.f;
    }
    float v = bf2f(h[(size_t)node * 256 + c]) * sc + sh;
    local += fmaxf(v, 0.f);
  }
  if (cur >= 0) atomicAdd(&Gsum[(size_t)cur * 256 + c], local);
}

__global__ __launch_bounds__(128) void k_fc(const float* __restrict__ Gsum,
    const int* __restrict__ Gcnt, const float* __restrict__ Wfc,
    const float* __restrict__ bfc, float* __restrict__ out) {
  int g = blockIdx.x, j = threadIdx.x;
  float inv = 1.0f / fmaxf((float)Gcnt[g], 1.0f);
  float acc = 0.f;
#pragma unroll 4
  for (int c = 0; c < 256; ++c) acc += Gsum[(size_t)g * 256 + c] * Wfc[c * 128 + j];
  out[(size_t)g * 128 + j] = acc * inv + bfc[j];
}

extern "C" void kernel_launch(void* const* d_in, const int* in_sizes, int n_in,
                              void* d_out, int out_size, void* d_ws, size_t ws_size,
                              hipStream_t stream) {
  const float* V   = (const float*)d_in[0];
  const void*  EI  = d_in[1];
  const void*  BAT = d_in[2];
  const float* W1  = (const float*)d_in[3];
  const float* b1  = (const float*)d_in[4];
  const float* g1  = (const float*)d_in[5];
  const float* be1 = (const float*)d_in[6];
  const float* W2  = (const float*)d_in[7];
  const float* b2  = (const float*)d_in[8];
  const float* g2  = (const float*)d_in[9];
  const float* be2 = (const float*)d_in[10];
  const float* Wfc = (const float*)d_in[11];
  const float* bfc = (const float*)d_in[12];
  float* out = (float*)d_out;
  const int E  = in_sizes[1] / 2;
  const int NE = E + NN;

  char* w = (char*)d_ws;
  size_t o = 0;
  auto alloc = [&](size_t bytes) -> char* {
    char* r = w + o;
    o = (o + bytes + 255) & ~(size_t)255;
    return r;
  };
  int*   flag   = (int*)alloc(4);
  int*   deg    = (int*)alloc((size_t)NN * 4);
  int*   cursor = (int*)alloc((size_t)NN * 4);
  int*   offs   = (int*)alloc((size_t)NN * 4);
  int*   bsum   = (int*)alloc(256 * 4);
  int*   csr_s  = (int*)alloc((size_t)NE * 4);
  float* csr_w  = (float*)alloc((size_t)NE * 4);
  float* dinv   = (float*)alloc((size_t)NN * 4);
  float* stats  = (float*)alloc(8 * 256 * 4);
  float *sums1 = stats, *sumsq1 = stats + 256, *sums2 = stats + 512, *sumsq2 = stats + 768;
  float *scale1 = stats + 1024, *shift1 = stats + 1280, *scale2 = stats + 1536, *shift2 = stats + 1792;
  float* Gsum   = (float*)alloc((size_t)NG * DH * 4);
  int*   Gcnt   = (int*)alloc(NG * 4);
  u16*   W1t    = (u16*)alloc((size_t)256 * DIN * 2);
  u16*   W2t    = (u16*)alloc((size_t)256 * DH * 2);
  u16*   Vb     = (u16*)alloc((size_t)NN * DIN * 2);
  u16*   agg1   = (u16*)alloc((size_t)NPAD * DIN * 2);   // bf16 A for GEMM1
  u16*   h1b    = (u16*)alloc((size_t)NN * DH * 2);
  u16*   h1n    = (u16*)alloc((size_t)NN * DH * 2);
  u16*   agg2   = (u16*)alloc((size_t)NPAD * DH * 2);    // bf16 A for GEMM2
  u16*   h2b    = (u16*)alloc((size_t)NN * DH * 2);
  (void)n_in; (void)out_size; (void)ws_size;

  hipMemsetAsync(deg, 0, (size_t)NN * 4, stream);
  hipMemsetAsync(cursor, 0, (size_t)NN * 4, stream);
  hipMemsetAsync(stats, 0, 4 * 256 * 4, stream);
  hipMemsetAsync(Gsum, 0, (size_t)NG * DH * 4, stream);
  hipMemsetAsync(Gcnt, 0, (size_t)NG * 4, stream);

  const int gE = (E + 255) / 256;
  const int gN = (NN + 255) / 256;

  k_detect<<<1, 64, 0, stream>>>((const int*)EI, flag);
  k_count<<<gE, 256, 0, stream>>>(EI, E, deg, flag);
  k_dinv<<<gN, 256, 0, stream>>>(deg, dinv);
  k_scan1<<<gN, 256, 0, stream>>>(deg, bsum);
  k_scan2<<<1, 256, 0, stream>>>(bsum, gN);
  k_scan3<<<gN, 256, 0, stream>>>(deg, bsum, offs);
  k_fill<<<gE, 256, 0, stream>>>(EI, E, dinv, offs, cursor, csr_s, csr_w, flag);
  k_self<<<gN, 256, 0, stream>>>(deg, dinv, offs, csr_s, csr_w);
  k_wt<<<(DIN * 256 + 255) / 256, 256, 0, stream>>>(W1, W1t, DIN);
  k_wt<<<(DH * 256 + 255) / 256, 256, 0, stream>>>(W2, W2t, DH);
  k_cast<<<(NN * DIN / 4 + 255) / 256, 256, 0, stream>>>(V, Vb, NN * DIN);

  k_agg<128><<<(NN + 3) / 4, 256, 0, stream>>>(Vb, offs, deg, csr_s, csr_w, agg1);
  k_mgemm<<<dim3((NN + 127) / 128, 2), 256, 0, stream>>>(agg1, W1t, b1, h1b, NN, DIN);
  k_stats<<<512, 256, 0, stream>>>(h1b, sums1, sumsq1);
  k_scale<<<1, 256, 0, stream>>>(sums1, sumsq1, g1, be1, scale1, shift1);
  k_normcast<<<(NN * DH / 4 + 255) / 256, 256, 0, stream>>>(h1b, scale1, shift1, h1n);

  k_agg<256><<<(NN + 3) / 4, 256, 0, stream>>>(h1n, offs, deg, csr_s, csr_w, agg2);
  k_mgemm<<<dim3((NN + 127) / 128, 2), 256, 0, stream>>>(agg2, W2t, b2, h2b, NN, DH);
  k_stats<<<512, 256, 0, stream>>>(h2b, sums2, sumsq2);
  k_scale<<<1, 256, 0, stream>>>(sums2, sumsq2, g2, be2, scale2, shift2);

  k_cnt<<<gN, 256, 0, stream>>>(BAT, Gcnt, flag);
  k_pool<<<(NN + 63) / 64, 256, 0, stream>>>(h2b, scale2, shift2, BAT, Gsum, flag);
  k_fc<<<NG, 128, 0, stream>>>(Gsum, Gcnt, Wfc, bfc, out);
}

// Round 3
// 551.591 us; speedup vs baseline: 1.5648x; 1.1427x over previous
//
#include <hip/hip_runtime.h>
#include <stdint.h>

typedef unsigned int u32;
typedef unsigned short u16;
typedef __attribute__((ext_vector_type(8))) short short8;
typedef __attribute__((ext_vector_type(4))) float f32x4;

#define NN   50000
#define NPAD 50048
#define NG   512
#define DIN  128
#define DH   256
#define BN_EPS 1e-5f

#define CAST_BLK 6250   // NN*DIN/4/256 exact
#define WT1_BLK  128    // DIN*256/256
#define WT2_BLK  256    // DH*256/256

__device__ __forceinline__ float bf2f(u16 u) {
  union { u32 i; float f; } v; v.i = ((u32)u) << 16; return v.f;
}
__device__ __forceinline__ u16 f2bf(float f) {
  union { float f; u32 i; } v; v.f = f;
  return (u16)((v.i + 0x7FFFu + ((v.i >> 16) & 1u)) >> 16);
}
__device__ __forceinline__ int load_idx(const void* p, long long i, int is64) {
  return is64 ? (int)((const long long*)p)[i] : ((const int*)p)[i];
}

__global__ void k_detect(const int* ei, int* flag) {
  if (threadIdx.x == 0 && blockIdx.x == 0) {
    int oddz = 0;
    for (int i = 0; i < 128; ++i) oddz += (ei[2 * i + 1] == 0) ? 1 : 0;
    *flag = (oddz == 128) ? 1 : 0;
  }
}

__global__ void k_count(const void* ei, int E, int* __restrict__ cnt, const int* flag) {
  int is64 = *flag;
  int e = blockIdx.x * blockDim.x + threadIdx.x;
  if (e < E) {
    int d = load_idx(ei, (long long)E + e, is64);
    atomicAdd(&cnt[d], 1);
  }
}

__global__ void k_scan1(const int* __restrict__ cnt, int* __restrict__ bsum) {
  __shared__ int s[256];
  int i = blockIdx.x * 256 + threadIdx.x;
  int v = (i < NN) ? (cnt[i] + 1) : 0;
  s[threadIdx.x] = v; __syncthreads();
  for (int st = 128; st > 0; st >>= 1) {
    if (threadIdx.x < st) s[threadIdx.x] += s[threadIdx.x + st];
    __syncthreads();
  }
  if (threadIdx.x == 0) bsum[blockIdx.x] = s[0];
}

__global__ void k_scan2(int* __restrict__ bsum, int nb) {
  __shared__ int s[256];
  int t = threadIdx.x;
  s[t] = (t < nb) ? bsum[t] : 0; __syncthreads();
  for (int off = 1; off < 256; off <<= 1) {
    int x = s[t];
    int y = (t >= off) ? s[t - off] : 0;
    __syncthreads();
    s[t] = x + y; __syncthreads();
  }
  if (t < nb) bsum[t] = (t == 0) ? 0 : s[t - 1];
}

// scan3: exclusive offsets + dinv fused
__global__ void k_scan3(const int* __restrict__ cnt, const int* __restrict__ bbase,
                        int* __restrict__ offs, float* __restrict__ dinv) {
  __shared__ int s[256];
  int t = threadIdx.x;
  int i = blockIdx.x * 256 + t;
  int v = (i < NN) ? (cnt[i] + 1) : 0;
  s[t] = v; __syncthreads();
  for (int off = 1; off < 256; off <<= 1) {
    int x = s[t];
    int y = (t >= off) ? s[t - off] : 0;
    __syncthreads();
    s[t] = x + y; __syncthreads();
  }
  if (i < NN) {
    offs[i] = bbase[blockIdx.x] + s[t] - v;
    dinv[i] = rsqrtf((float)v);
  }
}

// Fill CSR (u16 src only; weights recomputed at gather) + self-loops fused.
// cursor must be pre-initialized to offs (d2d copy).
__global__ void k_fill(const void* ei, int E, const int* __restrict__ offs,
                       const int* __restrict__ deg, int* __restrict__ cursor,
                       u16* __restrict__ csr_s, const int* flag) {
  int is64 = *flag;
  int e = blockIdx.x * blockDim.x + threadIdx.x;
  if (e < E) {
    int s = load_idx(ei, e, is64);
    int d = load_idx(ei, (long long)E + e, is64);
    int idx = atomicAdd(&cursor[d], 1);
    csr_s[idx] = (u16)s;
  } else {
    int i = e - E;
    if (i < NN) csr_s[offs[i] + deg[i]] = (u16)i;
  }
}

// Fused prep: V f32->bf16 cast, W1/W2 transpose+cast.
__global__ void k_prep(const float* __restrict__ V, const float* __restrict__ W1,
                       const float* __restrict__ W2, u16* __restrict__ Vb,
                       u16* __restrict__ W1t, u16* __restrict__ W2t) {
  int b = blockIdx.x;
  if (b < CAST_BLK) {
    int i = (b * 256 + threadIdx.x) * 4;
    float4 v = *(const float4*)(V + i);
    ushort4 o;
    o.x = f2bf(v.x); o.y = f2bf(v.y); o.z = f2bf(v.z); o.w = f2bf(v.w);
    *(ushort4*)(Vb + i) = o;
  } else if (b < CAST_BLK + WT1_BLK) {
    int i = (b - CAST_BLK) * 256 + threadIdx.x;
    int k = i >> 8, c = i & 255;
    W1t[c * DIN + k] = f2bf(W1[i]);
  } else {
    int i = (b - CAST_BLK - WT1_BLK) * 256 + threadIdx.x;
    int k = i >> 8, c = i & 255;
    W2t[c * DH + k] = f2bf(W2[i]);
  }
}

// Gather-aggregate, 16B/lane, multi-edge per wave, w = dinv[s]*dinv[node].
// BN=1: apply scale/shift+relu to gathered (pre-BN) values on the fly.
template <int D, int BN>
__global__ __launch_bounds__(256) void k_agg(const u16* __restrict__ in,
    const int* __restrict__ offs, const int* __restrict__ cnt,
    const u16* __restrict__ csr_s, const float* __restrict__ dinv,
    const float* __restrict__ scale, const float* __restrict__ shift,
    u16* __restrict__ out) {
  int node = (blockIdx.x * 256 + threadIdx.x) >> 6;
  int lane = threadIdx.x & 63;
  if (node >= NN) return;
  int beg = offs[node];
  int end = beg + cnt[node] + 1;
  float dinvn = dinv[node];
  float acc[8] = {};
  float scl[8], sft[8];
  if (BN) {
    int sub = (D == 128) ? (lane & 15) : (lane & 31);
#pragma unroll
    for (int j = 0; j < 8; ++j) {
      scl[j] = scale[sub * 8 + j];
      sft[j] = shift[sub * 8 + j];
    }
  }
  if (D == 128) {
    int grp = lane >> 4, sub = lane & 15;
    for (int e = beg + grp; e < end; e += 4) {
      int s = csr_s[e];
      float w = dinv[s] * dinvn;
      uint4 p = *(const uint4*)(in + (size_t)s * 128 + sub * 8);
      u32 pp[4] = {p.x, p.y, p.z, p.w};
#pragma unroll
      for (int j = 0; j < 4; ++j) {
        float v0 = bf2f((u16)(pp[j] & 0xFFFFu));
        float v1 = bf2f((u16)(pp[j] >> 16));
        if (BN) {
          v0 = fmaxf(v0 * scl[2 * j + 0] + sft[2 * j + 0], 0.f);
          v1 = fmaxf(v1 * scl[2 * j + 1] + sft[2 * j + 1], 0.f);
        }
        acc[2 * j + 0] += w * v0;
        acc[2 * j + 1] += w * v1;
      }
    }
#pragma unroll
    for (int j = 0; j < 8; ++j) {
      acc[j] += __shfl_xor(acc[j], 16, 64);
      acc[j] += __shfl_xor(acc[j], 32, 64);
    }
    if (lane < 16) {
      ushort4 o0, o1;
      o0.x = f2bf(acc[0]); o0.y = f2bf(acc[1]); o0.z = f2bf(acc[2]); o0.w = f2bf(acc[3]);
      o1.x = f2bf(acc[4]); o1.y = f2bf(acc[5]); o1.z = f2bf(acc[6]); o1.w = f2bf(acc[7]);
      *(ushort4*)(out + (size_t)node * 128 + lane * 8 + 0) = o0;
      *(ushort4*)(out + (size_t)node * 128 + lane * 8 + 4) = o1;
    }
  } else {
    int grp = lane >> 5, sub = lane & 31;
    for (int e = beg + grp; e < end; e += 2) {
      int s = csr_s[e];
      float w = dinv[s] * dinvn;
      uint4 p = *(const uint4*)(in + (size_t)s * 256 + sub * 8);
      u32 pp[4] = {p.x, p.y, p.z, p.w};
#pragma unroll
      for (int j = 0; j < 4; ++j) {
        float v0 = bf2f((u16)(pp[j] & 0xFFFFu));
        float v1 = bf2f((u16)(pp[j] >> 16));
        if (BN) {
          v0 = fmaxf(v0 * scl[2 * j + 0] + sft[2 * j + 0], 0.f);
          v1 = fmaxf(v1 * scl[2 * j + 1] + sft[2 * j + 1], 0.f);
        }
        acc[2 * j + 0] += w * v0;
        acc[2 * j + 1] += w * v1;
      }
    }
#pragma unroll
    for (int j = 0; j < 8; ++j) acc[j] += __shfl_xor(acc[j], 32, 64);
    if (lane < 32) {
      ushort4 o0, o1;
      o0.x = f2bf(acc[0]); o0.y = f2bf(acc[1]); o0.z = f2bf(acc[2]); o0.w = f2bf(acc[3]);
      o1.x = f2bf(acc[4]); o1.y = f2bf(acc[5]); o1.z = f2bf(acc[6]); o1.w = f2bf(acc[7]);
      *(ushort4*)(out + (size_t)node * 256 + lane * 8 + 0) = o0;
      *(ushort4*)(out + (size_t)node * 256 + lane * 8 + 4) = o1;
    }
  }
}

// bf16 MFMA GEMM + bias, fused BN-stats accumulation (sum/sumsq per column).
__global__ __launch_bounds__(256) void k_mgemm(const u16* __restrict__ A,
    const u16* __restrict__ Bt, const float* __restrict__ bias,
    u16* __restrict__ out, int M, int K,
    float* __restrict__ sums, float* __restrict__ sumsq) {
  __shared__ __align__(16) u16 As[128 * 32];
  __shared__ __align__(16) u16 Bs[128 * 32];
  int t = threadIdx.x;
  int l = t & 63;
  int w = t >> 6;
  int rowBase = blockIdx.x * 128;
  int colBase = blockIdx.y * 128;
  int wr = (w >> 1) * 64, wc = (w & 1) * 64;
  int rsel = l & 15, ksel = (l >> 4) * 8;

  f32x4 acc[4][4];
#pragma unroll
  for (int mi = 0; mi < 4; ++mi)
#pragma unroll
    for (int ni = 0; ni < 4; ++ni) acc[mi][ni] = (f32x4){0.f, 0.f, 0.f, 0.f};

  for (int k0 = 0; k0 < K; k0 += 32) {
#pragma unroll
    for (int c = 0; c < 2; ++c) {
      int idx = c * 256 + t;
      int row = idx >> 2;
      int kq = idx & 3;
      const u16* ga = A + (size_t)(rowBase + row) * K + k0 + kq * 8;
      const u16* gb = Bt + (size_t)(colBase + row) * K + k0 + kq * 8;
      __builtin_amdgcn_global_load_lds(
          (const __attribute__((address_space(1))) void*)ga,
          (__attribute__((address_space(3))) void*)(&As[idx * 8]), 16, 0, 0);
      __builtin_amdgcn_global_load_lds(
          (const __attribute__((address_space(1))) void*)gb,
          (__attribute__((address_space(3))) void*)(&Bs[idx * 8]), 16, 0, 0);
    }
    __syncthreads();
    short8 a[4], b[4];
#pragma unroll
    for (int mi = 0; mi < 4; ++mi)
      a[mi] = *(const short8*)(&As[(wr + mi * 16 + rsel) * 32 + ksel]);
#pragma unroll
    for (int ni = 0; ni < 4; ++ni)
      b[ni] = *(const short8*)(&Bs[(wc + ni * 16 + rsel) * 32 + ksel]);
#pragma unroll
    for (int mi = 0; mi < 4; ++mi)
#pragma unroll
      for (int ni = 0; ni < 4; ++ni)
        acc[mi][ni] = __builtin_amdgcn_mfma_f32_16x16x32_bf16(a[mi], b[ni], acc[mi][ni], 0, 0, 0);
    __syncthreads();
  }

#pragma unroll
  for (int ni = 0; ni < 4; ++ni) {
    int col = colBase + wc + ni * 16 + (l & 15);
    float bcol = bias[col];
    float s1 = 0.f, s2 = 0.f;
#pragma unroll
    for (int mi = 0; mi < 4; ++mi) {
#pragma unroll
      for (int r = 0; r < 4; ++r) {
        int row = rowBase + wr + mi * 16 + (l >> 4) * 4 + r;
        if (row < M) {
          float v = acc[mi][ni][r] + bcol;
          s1 += v; s2 += v * v;
          out[(size_t)row * 256 + col] = f2bf(v);
        }
      }
    }
    s1 += __shfl_xor(s1, 16, 64); s1 += __shfl_xor(s1, 32, 64);
    s2 += __shfl_xor(s2, 16, 64); s2 += __shfl_xor(s2, 32, 64);
    if (l < 16) {
      atomicAdd(&sums[col], s1);
      atomicAdd(&sumsq[col], s2);
    }
  }
}

__global__ void k_scale(const float* __restrict__ sum, const float* __restrict__ sumsq,
                        const float* __restrict__ g, const float* __restrict__ be,
                        float* __restrict__ scale, float* __restrict__ shift) {
  int c = threadIdx.x;
  float mean = sum[c] / (float)NN;
  float var = sumsq[c] / (float)NN - mean * mean;
  float sc = g[c] * rsqrtf(var + BN_EPS);
  scale[c] = sc;
  shift[c] = be[c] - mean * sc;
}

// Pool with fused per-graph node counting (thread c==0 counts run lengths).
__global__ __launch_bounds__(256) void k_pool(const u16* __restrict__ h,
    const float* __restrict__ scale, const float* __restrict__ shift,
    const void* batch, float* __restrict__ Gsum, int* __restrict__ Gcnt,
    const int* flag) {
  int is64 = *flag;
  int c = threadIdx.x;
  int nodeBase = blockIdx.x * 64;
  float sc = scale[c], sh = shift[c];
  float local = 0.f;
  int cur = -1, len = 0;
  int nmax = min(64, NN - nodeBase);
  for (int r = 0; r < nmax; ++r) {
    int node = nodeBase + r;
    int b = load_idx(batch, node, is64);
    if (b != cur) {
      if (cur >= 0) {
        atomicAdd(&Gsum[(size_t)cur * 256 + c], local);
        if (c == 0) atomicAdd(&Gcnt[cur], len);
      }
      cur = b; local = 0.f; len = 0;
    }
    float v = bf2f(h[(size_t)node * 256 + c]) * sc + sh;
    local += fmaxf(v, 0.f);
    len++;
  }
  if (cur >= 0) {
    atomicAdd(&Gsum[(size_t)cur * 256 + c], local);
    if (c == 0) atomicAdd(&Gcnt[cur], len);
  }
}

__global__ __launch_bounds__(128) void k_fc(const float* __restrict__ Gsum,
    const int* __restrict__ Gcnt, const float* __restrict__ Wfc,
    const float* __restrict__ bfc, float* __restrict__ out) {
  int g = blockIdx.x, j = threadIdx.x;
  float inv = 1.0f / fmaxf((float)Gcnt[g], 1.0f);
  float acc = 0.f;
#pragma unroll 4
  for (int c = 0; c < 256; ++c) acc += Gsum[(size_t)g * 256 + c] * Wfc[c * 128 + j];
  out[(size_t)g * 128 + j] = acc * inv + bfc[j];
}

extern "C" void kernel_launch(void* const* d_in, const int* in_sizes, int n_in,
                              void* d_out, int out_size, void* d_ws, size_t ws_size,
                              hipStream_t stream) {
  const float* V   = (const float*)d_in[0];
  const void*  EI  = d_in[1];
  const void*  BAT = d_in[2];
  const float* W1  = (const float*)d_in[3];
  const float* b1  = (const float*)d_in[4];
  const float* g1  = (const float*)d_in[5];
  const float* be1 = (const float*)d_in[6];
  const float* W2  = (const float*)d_in[7];
  const float* b2  = (const float*)d_in[8];
  const float* g2  = (const float*)d_in[9];
  const float* be2 = (const float*)d_in[10];
  const float* Wfc = (const float*)d_in[11];
  const float* bfc = (const float*)d_in[12];
  float* out = (float*)d_out;
  const int E  = in_sizes[1] / 2;
  const int NE = E + NN;

  char* w = (char*)d_ws;
  size_t o = 0;
  auto alloc = [&](size_t bytes) -> char* {
    char* r = w + o;
    o = (o + bytes + 255) & ~(size_t)255;
    return r;
  };
  int*   flag   = (int*)alloc(4);
  int*   deg    = (int*)alloc((size_t)NN * 4);
  int*   cursor = (int*)alloc((size_t)NN * 4);
  int*   offs   = (int*)alloc((size_t)NN * 4);
  int*   bsum   = (int*)alloc(256 * 4);
  u16*   csr_s  = (u16*)alloc((size_t)NE * 2);
  float* dinv   = (float*)alloc((size_t)NN * 4);
  float* stats  = (float*)alloc(8 * 256 * 4);
  float *sums1 = stats, *sumsq1 = stats + 256, *sums2 = stats + 512, *sumsq2 = stats + 768;
  float *scale1 = stats + 1024, *shift1 = stats + 1280, *scale2 = stats + 1536, *shift2 = stats + 1792;
  float* Gsum   = (float*)alloc((size_t)NG * DH * 4);
  int*   Gcnt   = (int*)alloc(NG * 4);
  u16*   W1t    = (u16*)alloc((size_t)256 * DIN * 2);
  u16*   W2t    = (u16*)alloc((size_t)256 * DH * 2);
  u16*   Vb     = (u16*)alloc((size_t)NN * DIN * 2);
  u16*   agg1   = (u16*)alloc((size_t)NPAD * DIN * 2);
  u16*   h1b    = (u16*)alloc((size_t)NN * DH * 2);
  u16*   agg2   = (u16*)alloc((size_t)NPAD * DH * 2);
  u16*   h2b    = (u16*)alloc((size_t)NN * DH * 2);
  (void)n_in; (void)out_size; (void)ws_size;

  hipMemsetAsync(deg, 0, (size_t)NN * 4, stream);
  hipMemsetAsync(stats, 0, 4 * 256 * 4, stream);
  hipMemsetAsync(Gsum, 0, (size_t)NG * DH * 4, stream);
  hipMemsetAsync(Gcnt, 0, (size_t)NG * 4, stream);

  const int gE = (E + 255) / 256;
  const int gN = (NN + 255) / 256;

  k_detect<<<1, 64, 0, stream>>>((const int*)EI, flag);
  k_count<<<gE, 256, 0, stream>>>(EI, E, deg, flag);
  k_scan1<<<gN, 256, 0, stream>>>(deg, bsum);
  k_scan2<<<1, 256, 0, stream>>>(bsum, gN);
  k_scan3<<<gN, 256, 0, stream>>>(deg, bsum, offs, dinv);
  hipMemcpyAsync(cursor, offs, (size_t)NN * 4, hipMemcpyDeviceToDevice, stream);
  k_fill<<<(NE + 255) / 256, 256, 0, stream>>>(EI, E, offs, deg, cursor, csr_s, flag);
  k_prep<<<CAST_BLK + WT1_BLK + WT2_BLK, 256, 0, stream>>>(V, W1, W2, Vb, W1t, W2t);

  k_agg<128, 0><<<(NN + 3) / 4, 256, 0, stream>>>(Vb, offs, deg, csr_s, dinv,
                                                  nullptr, nullptr, agg1);
  k_mgemm<<<dim3((NN + 127) / 128, 2), 256, 0, stream>>>(agg1, W1t, b1, h1b, NN, DIN,
                                                         sums1, sumsq1);
  k_scale<<<1, 256, 0, stream>>>(sums1, sumsq1, g1, be1, scale1, shift1);

  k_agg<256, 1><<<(NN + 3) / 4, 256, 0, stream>>>(h1b, offs, deg, csr_s, dinv,
                                                  scale1, shift1, agg2);
  k_mgemm<<<dim3((NN + 127) / 128, 2), 256, 0, stream>>>(agg2, W2t, b2, h2b, NN, DH,
                                                         sums2, sumsq2);
  k_scale<<<1, 256, 0, stream>>>(sums2, sumsq2, g2, be2, scale2, shift2);

  k_pool<<<(NN + 63) / 64, 256, 0, stream>>>(h2b, scale2, shift2, BAT, Gsum, Gcnt, flag);
  k_fc<<<NG, 128, 0, stream>>>(Gsum, Gcnt, Wfc, bfc, out);
}

// Round 4
// 413.289 us; speedup vs baseline: 2.0884x; 1.3346x over previous
//
#include <hip/hip_runtime.h>
#include <stdint.h>

typedef unsigned int u32;
typedef unsigned short u16;
typedef __attribute__((ext_vector_type(8))) short short8;
typedef __attribute__((ext_vector_type(4))) float f32x4;

#define NN   50000
#define NPAD 50048
#define NG   512
#define DIN  128
#define DH   256
#define BN_EPS 1e-5f
#define NB   196          // coarse dst buckets of 256 nodes
#define EPB  4096         // edges per block in binning kernels
#define WCAP 24576        // LDS staging capacity (u16) per window

#define CAST_BLK 6250
#define WT1_BLK  128
#define WT2_BLK  256

__device__ __forceinline__ float bf2f(u16 u) {
  union { u32 i; float f; } v; v.i = ((u32)u) << 16; return v.f;
}
__device__ __forceinline__ u16 f2bf(float f) {
  union { float f; u32 i; } v; v.f = f;
  return (u16)((v.i + 0x7FFFu + ((v.i >> 16) & 1u)) >> 16);
}
__device__ __forceinline__ int load_idx(const void* p, long long i, int is64) {
  return is64 ? (int)((const long long*)p)[i] : ((const int*)p)[i];
}

__global__ void k_detect(const int* ei, int* flag) {
  if (threadIdx.x == 0 && blockIdx.x == 0) {
    int oddz = 0;
    for (int i = 0; i < 128; ++i) oddz += (ei[2 * i + 1] == 0) ? 1 : 0;
    *flag = (oddz == 128) ? 1 : 0;
  }
}

// Coarse histogram: dst>>8 -> 196 buckets, per-block LDS then global.
__global__ __launch_bounds__(256) void k_bcnt(const void* ei, int E,
    int* __restrict__ bcnt, const int* flag) {
  __shared__ int h[NB];
  int is64 = *flag;
  int t = threadIdx.x;
  for (int i = t; i < NB; i += 256) h[i] = 0;
  __syncthreads();
  long long base = (long long)blockIdx.x * EPB + t * 16;
#pragma unroll
  for (int j = 0; j < 16; ++j) {
    long long e = base + j;
    if (e < E) {
      int d = load_idx(ei, (long long)E + e, is64);
      atomicAdd(&h[d >> 8], 1);
    }
  }
  __syncthreads();
  for (int i = t; i < NB; i += 256)
    if (h[i]) atomicAdd(&bcnt[i], h[i]);
}

// Exclusive scan of 196 bucket counts; init bcur = bbase.
__global__ void k_bscan(const int* __restrict__ bcnt, int* __restrict__ bbase,
                        int* __restrict__ bcur) {
  __shared__ int s[256];
  int t = threadIdx.x;
  s[t] = (t < NB) ? bcnt[t] : 0; __syncthreads();
  for (int off = 1; off < 256; off <<= 1) {
    int x = s[t];
    int y = (t >= off) ? s[t - off] : 0;
    __syncthreads();
    s[t] = x + y; __syncthreads();
  }
  if (t < NB) {
    int ex = (t == 0) ? 0 : s[t - 1];
    bbase[t] = ex;
    bcur[t] = ex;
  }
}

// Scatter packed records (src<<8 | dst&255) into bucket-contiguous ranges.
__global__ __launch_bounds__(256) void k_bfill(const void* ei, int E,
    int* __restrict__ bcur, u32* __restrict__ recs, const int* flag) {
  __shared__ int h[NB];
  __shared__ int lbase[NB];
  __shared__ int lcur[NB];
  int is64 = *flag;
  int t = threadIdx.x;
  for (int i = t; i < NB; i += 256) h[i] = 0;
  __syncthreads();
  u32 rr[16];
  int bb[16];
  long long base = (long long)blockIdx.x * EPB + t * 16;
#pragma unroll
  for (int j = 0; j < 16; ++j) {
    long long e = base + j;
    if (e < E) {
      int s = load_idx(ei, e, is64);
      int d = load_idx(ei, (long long)E + e, is64);
      int b = d >> 8;
      rr[j] = ((u32)s << 8) | (u32)(d & 255);
      bb[j] = b;
      atomicAdd(&h[b], 1);
    } else bb[j] = -1;
  }
  __syncthreads();
  for (int i = t; i < NB; i += 256) {
    lbase[i] = h[i] ? atomicAdd(&bcur[i], h[i]) : 0;
    lcur[i] = 0;
  }
  __syncthreads();
#pragma unroll
  for (int j = 0; j < 16; ++j) {
    if (bb[j] >= 0) {
      int loc = atomicAdd(&lcur[bb[j]], 1);
      recs[lbase[bb[j]] + loc] = rr[j];
    }
  }
}

// Per-bucket degree from records.
__global__ __launch_bounds__(512) void k_degw(const u32* __restrict__ recs,
    const int* __restrict__ bbase, const int* __restrict__ bcnt,
    int* __restrict__ deg) {
  __shared__ int h[256];
  int b = blockIdx.x;
  int t = threadIdx.x;
  if (t < 256) h[t] = 0;
  __syncthreads();
  int rb = bbase[b], cnt = bcnt[b];
  for (int i = t; i < cnt; i += 512) atomicAdd(&h[recs[rb + i] & 255u], 1);
  __syncthreads();
  int node = b * 256 + t;
  if (t < 256 && node < NN) deg[node] = h[t];
}

__global__ void k_scan1(const int* __restrict__ cnt, int* __restrict__ bsum) {
  __shared__ int s[256];
  int i = blockIdx.x * 256 + threadIdx.x;
  int v = (i < NN) ? (cnt[i] + 1) : 0;
  s[threadIdx.x] = v; __syncthreads();
  for (int st = 128; st > 0; st >>= 1) {
    if (threadIdx.x < st) s[threadIdx.x] += s[threadIdx.x + st];
    __syncthreads();
  }
  if (threadIdx.x == 0) bsum[blockIdx.x] = s[0];
}

__global__ void k_scan2(int* __restrict__ bsum, int nb) {
  __shared__ int s[256];
  int t = threadIdx.x;
  s[t] = (t < nb) ? bsum[t] : 0; __syncthreads();
  for (int off = 1; off < 256; off <<= 1) {
    int x = s[t];
    int y = (t >= off) ? s[t - off] : 0;
    __syncthreads();
    s[t] = x + y; __syncthreads();
  }
  if (t < nb) bsum[t] = (t == 0) ? 0 : s[t - 1];
}

__global__ void k_scan3(const int* __restrict__ cnt, const int* __restrict__ bbase,
                        int* __restrict__ offs, float* __restrict__ dinv) {
  __shared__ int s[256];
  int t = threadIdx.x;
  int i = blockIdx.x * 256 + t;
  int v = (i < NN) ? (cnt[i] + 1) : 0;
  s[t] = v; __syncthreads();
  for (int off = 1; off < 256; off <<= 1) {
    int x = s[t];
    int y = (t >= off) ? s[t - off] : 0;
    __syncthreads();
    s[t] = x + y; __syncthreads();
  }
  if (i < NN) {
    offs[i] = bbase[blockIdx.x] + s[t] - v;
    dinv[i] = rsqrtf((float)v);
  }
}

// Stage one 256-node csr window in LDS, fill from records + self-loops,
// flush contiguously.
__global__ __launch_bounds__(512) void k_window(const u32* __restrict__ recs,
    const int* __restrict__ bbase, const int* __restrict__ bcnt,
    const int* __restrict__ offs, u16* __restrict__ csr_s) {
  __shared__ u16 stage[WCAP];
  __shared__ int wcur[256];
  __shared__ int woff[256];
  __shared__ int info[3];  // gbase, winsize, ovf
  int b = blockIdx.x;
  int t = threadIdx.x;
  int nodeBase = b * 256;
  int nin = min(256, NN - nodeBase);
  if (t == 0) info[0] = offs[nodeBase];
  __syncthreads();
  int gbase = info[0];
  if (t < 256) {
    if (t < nin) {
      woff[t] = offs[nodeBase + t] - gbase;
      wcur[t] = 0;
    } else { woff[t] = 0; wcur[t] = 0; }
  }
  if (t == 0) {
    int lastNode = nodeBase + nin - 1;
    // winsize = last node's slot-end relative to gbase (deg known post-fill;
    // use offs difference: end = offs[last] - gbase + (deg+1)); compute later
    info[2] = 0;
  }
  __syncthreads();
  int rb = bbase[b], cnt = bcnt[b];
  // conservative overflow check: winsize = woff[nin-1] + (slots of last node).
  // We don't know deg yet; use cnt + nin (total slots) as exact winsize.
  int winsize = cnt + nin;
  bool ovf = winsize > WCAP;
  if (!ovf) {
    for (int i = t; i < cnt; i += 512) {
      u32 r = recs[rb + i];
      int d = r & 255u;
      int loc = atomicAdd(&wcur[d], 1);
      stage[woff[d] + loc] = (u16)(r >> 8);
    }
    __syncthreads();
    if (t < nin) stage[woff[t] + wcur[t]] = (u16)(nodeBase + t);  // self-loop
    __syncthreads();
    for (int i = t; i < winsize; i += 512) csr_s[gbase + i] = stage[i];
  } else {
    for (int i = t; i < cnt; i += 512) {
      u32 r = recs[rb + i];
      int d = r & 255u;
      int loc = atomicAdd(&wcur[d], 1);
      csr_s[gbase + woff[d] + loc] = (u16)(r >> 8);
    }
    __syncthreads();
    if (t < nin) csr_s[gbase + woff[t] + wcur[t]] = (u16)(nodeBase + t);
  }
}

__global__ void k_prep(const float* __restrict__ V, const float* __restrict__ W1,
                       const float* __restrict__ W2, u16* __restrict__ Vb,
                       u16* __restrict__ W1t, u16* __restrict__ W2t) {
  int b = blockIdx.x;
  if (b < CAST_BLK) {
    int i = (b * 256 + threadIdx.x) * 4;
    float4 v = *(const float4*)(V + i);
    ushort4 o;
    o.x = f2bf(v.x); o.y = f2bf(v.y); o.z = f2bf(v.z); o.w = f2bf(v.w);
    *(ushort4*)(Vb + i) = o;
  } else if (b < CAST_BLK + WT1_BLK) {
    int i = (b - CAST_BLK) * 256 + threadIdx.x;
    int k = i >> 8, c = i & 255;
    W1t[c * DIN + k] = f2bf(W1[i]);
  } else {
    int i = (b - CAST_BLK - WT1_BLK) * 256 + threadIdx.x;
    int k = i >> 8, c = i & 255;
    W2t[c * DH + k] = f2bf(W2[i]);
  }
}

template <int D, int BN>
__global__ __launch_bounds__(256) void k_agg(const u16* __restrict__ in,
    const int* __restrict__ offs, const int* __restrict__ cnt,
    const u16* __restrict__ csr_s, const float* __restrict__ dinv,
    const float* __restrict__ scale, const float* __restrict__ shift,
    u16* __restrict__ out) {
  int node = (blockIdx.x * 256 + threadIdx.x) >> 6;
  int lane = threadIdx.x & 63;
  if (node >= NN) return;
  int beg = offs[node];
  int end = beg + cnt[node] + 1;
  float dinvn = dinv[node];
  float acc[8] = {};
  float scl[8], sft[8];
  if (BN) {
    int sub = (D == 128) ? (lane & 15) : (lane & 31);
#pragma unroll
    for (int j = 0; j < 8; ++j) {
      scl[j] = scale[sub * 8 + j];
      sft[j] = shift[sub * 8 + j];
    }
  }
  if (D == 128) {
    int grp = lane >> 4, sub = lane & 15;
    for (int e = beg + grp; e < end; e += 4) {
      int s = csr_s[e];
      float w = dinv[s] * dinvn;
      uint4 p = *(const uint4*)(in + (size_t)s * 128 + sub * 8);
      u32 pp[4] = {p.x, p.y, p.z, p.w};
#pragma unroll
      for (int j = 0; j < 4; ++j) {
        float v0 = bf2f((u16)(pp[j] & 0xFFFFu));
        float v1 = bf2f((u16)(pp[j] >> 16));
        if (BN) {
          v0 = fmaxf(v0 * scl[2 * j + 0] + sft[2 * j + 0], 0.f);
          v1 = fmaxf(v1 * scl[2 * j + 1] + sft[2 * j + 1], 0.f);
        }
        acc[2 * j + 0] += w * v0;
        acc[2 * j + 1] += w * v1;
      }
    }
#pragma unroll
    for (int j = 0; j < 8; ++j) {
      acc[j] += __shfl_xor(acc[j], 16, 64);
      acc[j] += __shfl_xor(acc[j], 32, 64);
    }
    if (lane < 16) {
      ushort4 o0, o1;
      o0.x = f2bf(acc[0]); o0.y = f2bf(acc[1]); o0.z = f2bf(acc[2]); o0.w = f2bf(acc[3]);
      o1.x = f2bf(acc[4]); o1.y = f2bf(acc[5]); o1.z = f2bf(acc[6]); o1.w = f2bf(acc[7]);
      *(ushort4*)(out + (size_t)node * 128 + lane * 8 + 0) = o0;
      *(ushort4*)(out + (size_t)node * 128 + lane * 8 + 4) = o1;
    }
  } else {
    int grp = lane >> 5, sub = lane & 31;
    for (int e = beg + grp; e < end; e += 2) {
      int s = csr_s[e];
      float w = dinv[s] * dinvn;
      uint4 p = *(const uint4*)(in + (size_t)s * 256 + sub * 8);
      u32 pp[4] = {p.x, p.y, p.z, p.w};
#pragma unroll
      for (int j = 0; j < 4; ++j) {
        float v0 = bf2f((u16)(pp[j] & 0xFFFFu));
        float v1 = bf2f((u16)(pp[j] >> 16));
        if (BN) {
          v0 = fmaxf(v0 * scl[2 * j + 0] + sft[2 * j + 0], 0.f);
          v1 = fmaxf(v1 * scl[2 * j + 1] + sft[2 * j + 1], 0.f);
        }
        acc[2 * j + 0] += w * v0;
        acc[2 * j + 1] += w * v1;
      }
    }
#pragma unroll
    for (int j = 0; j < 8; ++j) acc[j] += __shfl_xor(acc[j], 32, 64);
    if (lane < 32) {
      ushort4 o0, o1;
      o0.x = f2bf(acc[0]); o0.y = f2bf(acc[1]); o0.z = f2bf(acc[2]); o0.w = f2bf(acc[3]);
      o1.x = f2bf(acc[4]); o1.y = f2bf(acc[5]); o1.z = f2bf(acc[6]); o1.w = f2bf(acc[7]);
      *(ushort4*)(out + (size_t)node * 256 + lane * 8 + 0) = o0;
      *(ushort4*)(out + (size_t)node * 256 + lane * 8 + 4) = o1;
    }
  }
}

__global__ __launch_bounds__(256) void k_mgemm(const u16* __restrict__ A,
    const u16* __restrict__ Bt, const float* __restrict__ bias,
    u16* __restrict__ out, int M, int K,
    float* __restrict__ sums, float* __restrict__ sumsq) {
  __shared__ __align__(16) u16 As[128 * 32];
  __shared__ __align__(16) u16 Bs[128 * 32];
  int t = threadIdx.x;
  int l = t & 63;
  int w = t >> 6;
  int rowBase = blockIdx.x * 128;
  int colBase = blockIdx.y * 128;
  int wr = (w >> 1) * 64, wc = (w & 1) * 64;
  int rsel = l & 15, ksel = (l >> 4) * 8;

  f32x4 acc[4][4];
#pragma unroll
  for (int mi = 0; mi < 4; ++mi)
#pragma unroll
    for (int ni = 0; ni < 4; ++ni) acc[mi][ni] = (f32x4){0.f, 0.f, 0.f, 0.f};

  for (int k0 = 0; k0 < K; k0 += 32) {
#pragma unroll
    for (int c = 0; c < 2; ++c) {
      int idx = c * 256 + t;
      int row = idx >> 2;
      int kq = idx & 3;
      const u16* ga = A + (size_t)(rowBase + row) * K + k0 + kq * 8;
      const u16* gb = Bt + (size_t)(colBase + row) * K + k0 + kq * 8;
      __builtin_amdgcn_global_load_lds(
          (const __attribute__((address_space(1))) void*)ga,
          (__attribute__((address_space(3))) void*)(&As[idx * 8]), 16, 0, 0);
      __builtin_amdgcn_global_load_lds(
          (const __attribute__((address_space(1))) void*)gb,
          (__attribute__((address_space(3))) void*)(&Bs[idx * 8]), 16, 0, 0);
    }
    __syncthreads();
    short8 a[4], b[4];
#pragma unroll
    for (int mi = 0; mi < 4; ++mi)
      a[mi] = *(const short8*)(&As[(wr + mi * 16 + rsel) * 32 + ksel]);
#pragma unroll
    for (int ni = 0; ni < 4; ++ni)
      b[ni] = *(const short8*)(&Bs[(wc + ni * 16 + rsel) * 32 + ksel]);
#pragma unroll
    for (int mi = 0; mi < 4; ++mi)
#pragma unroll
      for (int ni = 0; ni < 4; ++ni)
        acc[mi][ni] = __builtin_amdgcn_mfma_f32_16x16x32_bf16(a[mi], b[ni], acc[mi][ni], 0, 0, 0);
    __syncthreads();
  }

#pragma unroll
  for (int ni = 0; ni < 4; ++ni) {
    int col = colBase + wc + ni * 16 + (l & 15);
    float bcol = bias[col];
    float s1 = 0.f, s2 = 0.f;
#pragma unroll
    for (int mi = 0; mi < 4; ++mi) {
#pragma unroll
      for (int r = 0; r < 4; ++r) {
        int row = rowBase + wr + mi * 16 + (l >> 4) * 4 + r;
        if (row < M) {
          float v = acc[mi][ni][r] + bcol;
          s1 += v; s2 += v * v;
          out[(size_t)row * 256 + col] = f2bf(v);
        }
      }
    }
    s1 += __shfl_xor(s1, 16, 64); s1 += __shfl_xor(s1, 32, 64);
    s2 += __shfl_xor(s2, 16, 64); s2 += __shfl_xor(s2, 32, 64);
    if (l < 16) {
      atomicAdd(&sums[col], s1);
      atomicAdd(&sumsq[col], s2);
    }
  }
}

__global__ void k_scale(const float* __restrict__ sum, const float* __restrict__ sumsq,
                        const float* __restrict__ g, const float* __restrict__ be,
                        float* __restrict__ scale, float* __restrict__ shift) {
  int c = threadIdx.x;
  float mean = sum[c] / (float)NN;
  float var = sumsq[c] / (float)NN - mean * mean;
  float sc = g[c] * rsqrtf(var + BN_EPS);
  scale[c] = sc;
  shift[c] = be[c] - mean * sc;
}

__global__ __launch_bounds__(256) void k_pool(const u16* __restrict__ h,
    const float* __restrict__ scale, const float* __restrict__ shift,
    const void* batch, float* __restrict__ Gsum, int* __restrict__ Gcnt,
    const int* flag) {
  int is64 = *flag;
  int c = threadIdx.x;
  int nodeBase = blockIdx.x * 64;
  float sc = scale[c], sh = shift[c];
  float local = 0.f;
  int cur = -1, len = 0;
  int nmax = min(64, NN - nodeBase);
  for (int r = 0; r < nmax; ++r) {
    int node = nodeBase + r;
    int b = load_idx(batch, node, is64);
    if (b != cur) {
      if (cur >= 0) {
        atomicAdd(&Gsum[(size_t)cur * 256 + c], local);
        if (c == 0) atomicAdd(&Gcnt[cur], len);
      }
      cur = b; local = 0.f; len = 0;
    }
    float v = bf2f(h[(size_t)node * 256 + c]) * sc + sh;
    local += fmaxf(v, 0.f);
    len++;
  }
  if (cur >= 0) {
    atomicAdd(&Gsum[(size_t)cur * 256 + c], local);
    if (c == 0) atomicAdd(&Gcnt[cur], len);
  }
}

__global__ __launch_bounds__(128) void k_fc(const float* __restrict__ Gsum,
    const int* __restrict__ Gcnt, const float* __restrict__ Wfc,
    const float* __restrict__ bfc, float* __restrict__ out) {
  int g = blockIdx.x, j = threadIdx.x;
  float inv = 1.0f / fmaxf((float)Gcnt[g], 1.0f);
  float acc = 0.f;
#pragma unroll 4
  for (int c = 0; c < 256; ++c) acc += Gsum[(size_t)g * 256 + c] * Wfc[c * 128 + j];
  out[(size_t)g * 128 + j] = acc * inv + bfc[j];
}

extern "C" void kernel_launch(void* const* d_in, const int* in_sizes, int n_in,
                              void* d_out, int out_size, void* d_ws, size_t ws_size,
                              hipStream_t stream) {
  const float* V   = (const float*)d_in[0];
  const void*  EI  = d_in[1];
  const void*  BAT = d_in[2];
  const float* W1  = (const float*)d_in[3];
  const float* b1  = (const float*)d_in[4];
  const float* g1  = (const float*)d_in[5];
  const float* be1 = (const float*)d_in[6];
  const float* W2  = (const float*)d_in[7];
  const float* b2  = (const float*)d_in[8];
  const float* g2  = (const float*)d_in[9];
  const float* be2 = (const float*)d_in[10];
  const float* Wfc = (const float*)d_in[11];
  const float* bfc = (const float*)d_in[12];
  float* out = (float*)d_out;
  const int E  = in_sizes[1] / 2;
  const int NE = E + NN;

  char* w = (char*)d_ws;
  size_t o = 0;
  auto alloc = [&](size_t bytes) -> char* {
    char* r = w + o;
    o = (o + bytes + 255) & ~(size_t)255;
    return r;
  };
  int*   flag   = (int*)alloc(4);
  int*   deg    = (int*)alloc((size_t)NN * 4);
  int*   offs   = (int*)alloc((size_t)NN * 4);
  int*   bsum   = (int*)alloc(256 * 4);
  int*   bcnt   = (int*)alloc(NB * 4);
  int*   bbase  = (int*)alloc(NB * 4);
  int*   bcur   = (int*)alloc(NB * 4);
  u32*   recs   = (u32*)alloc((size_t)E * 4);
  u16*   csr_s  = (u16*)alloc((size_t)NE * 2);
  float* dinv   = (float*)alloc((size_t)NN * 4);
  float* stats  = (float*)alloc(8 * 256 * 4);
  float *sums1 = stats, *sumsq1 = stats + 256, *sums2 = stats + 512, *sumsq2 = stats + 768;
  float *scale1 = stats + 1024, *shift1 = stats + 1280, *scale2 = stats + 1536, *shift2 = stats + 1792;
  float* Gsum   = (float*)alloc((size_t)NG * DH * 4);
  int*   Gcnt   = (int*)alloc(NG * 4);
  u16*   W1t    = (u16*)alloc((size_t)256 * DIN * 2);
  u16*   W2t    = (u16*)alloc((size_t)256 * DH * 2);
  u16*   Vb     = (u16*)alloc((size_t)NN * DIN * 2);
  u16*   agg1   = (u16*)alloc((size_t)NPAD * DIN * 2);
  u16*   h1b    = (u16*)alloc((size_t)NN * DH * 2);
  u16*   agg2   = (u16*)alloc((size_t)NPAD * DH * 2);
  u16*   h2b    = (u16*)alloc((size_t)NN * DH * 2);
  (void)n_in; (void)out_size; (void)ws_size;

  hipMemsetAsync(bcnt, 0, NB * 4, stream);
  hipMemsetAsync(stats, 0, 4 * 256 * 4, stream);
  hipMemsetAsync(Gsum, 0, (size_t)NG * DH * 4, stream);
  hipMemsetAsync(Gcnt, 0, (size_t)NG * 4, stream);

  const int gB = (E + EPB - 1) / EPB;
  const int gN = (NN + 255) / 256;

  k_detect<<<1, 64, 0, stream>>>((const int*)EI, flag);
  k_bcnt<<<gB, 256, 0, stream>>>(EI, E, bcnt, flag);
  k_bscan<<<1, 256, 0, stream>>>(bcnt, bbase, bcur);
  k_bfill<<<gB, 256, 0, stream>>>(EI, E, bcur, recs, flag);
  k_degw<<<NB, 512, 0, stream>>>(recs, bbase, bcnt, deg);
  k_scan1<<<gN, 256, 0, stream>>>(deg, bsum);
  k_scan2<<<1, 256, 0, stream>>>(bsum, gN);
  k_scan3<<<gN, 256, 0, stream>>>(deg, bsum, offs, dinv);
  k_window<<<NB, 512, 0, stream>>>(recs, bbase, bcnt, offs, csr_s);
  k_prep<<<CAST_BLK + WT1_BLK + WT2_BLK, 256, 0, stream>>>(V, W1, W2, Vb, W1t, W2t);

  k_agg<128, 0><<<(NN + 3) / 4, 256, 0, stream>>>(Vb, offs, deg, csr_s, dinv,
                                                  nullptr, nullptr, agg1);
  k_mgemm<<<dim3((NN + 127) / 128, 2), 256, 0, stream>>>(agg1, W1t, b1, h1b, NN, DIN,
                                                         sums1, sumsq1);
  k_scale<<<1, 256, 0, stream>>>(sums1, sumsq1, g1, be1, scale1, shift1);

  k_agg<256, 1><<<(NN + 3) / 4, 256, 0, stream>>>(h1b, offs, deg, csr_s, dinv,
                                                  scale1, shift1, agg2);
  k_mgemm<<<dim3((NN + 127) / 128, 2), 256, 0, stream>>>(agg2, W2t, b2, h2b, NN, DH,
                                                         sums2, sumsq2);
  k_scale<<<1, 256, 0, stream>>>(sums2, sumsq2, g2, be2, scale2, shift2);

  k_pool<<<(NN + 63) / 64, 256, 0, stream>>>(h2b, scale2, shift2, BAT, Gsum, Gcnt, flag);
  k_fc<<<NG, 128, 0, stream>>>(Gsum, Gcnt, Wfc, bfc, out);
}

// Round 5
// 390.649 us; speedup vs baseline: 2.2095x; 1.0580x over previous
//
#include <hip/hip_runtime.h>
#include <stdint.h>

typedef unsigned int u32;
typedef unsigned short u16;
typedef __attribute__((ext_vector_type(8))) short short8;
typedef __attribute__((ext_vector_type(4))) float f32x4;

#define NN   50000
#define NPAD 50048
#define NG   512
#define DIN  128
#define DH   256
#define BN_EPS 1e-5f
#define NB   196          // coarse dst buckets of 256 nodes
#define EPB  4096         // edges per block in binning kernels
#define WCAP 24576        // LDS staging capacity (u16) per window

#define CAST_BLK 6250
#define WT1_BLK  128
#define WT2_BLK  256

__device__ __forceinline__ float bf2f(u16 u) {
  union { u32 i; float f; } v; v.i = ((u32)u) << 16; return v.f;
}
__device__ __forceinline__ float bflo(u32 p) {
  union { u32 i; float f; } v; v.i = p << 16; return v.f;
}
__device__ __forceinline__ float bfhi(u32 p) {
  union { u32 i; float f; } v; v.i = p & 0xFFFF0000u; return v.f;
}
__device__ __forceinline__ u16 f2bf(float f) {
  union { float f; u32 i; } v; v.f = f;
  return (u16)((v.i + 0x7FFFu + ((v.i >> 16) & 1u)) >> 16);
}
__device__ __forceinline__ int load_idx(const void* p, long long i, int is64) {
  return is64 ? (int)((const long long*)p)[i] : ((const int*)p)[i];
}

__global__ void k_detect(const int* ei, int* flag) {
  if (threadIdx.x == 0 && blockIdx.x == 0) {
    int oddz = 0;
    for (int i = 0; i < 128; ++i) oddz += (ei[2 * i + 1] == 0) ? 1 : 0;
    *flag = (oddz == 128) ? 1 : 0;
  }
}

__global__ __launch_bounds__(256) void k_bcnt(const void* ei, int E,
    int* __restrict__ bcnt, const int* flag) {
  __shared__ int h[NB];
  int is64 = *flag;
  int t = threadIdx.x;
  for (int i = t; i < NB; i += 256) h[i] = 0;
  __syncthreads();
  long long base = (long long)blockIdx.x * EPB + t * 16;
#pragma unroll
  for (int j = 0; j < 16; ++j) {
    long long e = base + j;
    if (e < E) {
      int d = load_idx(ei, (long long)E + e, is64);
      atomicAdd(&h[d >> 8], 1);
    }
  }
  __syncthreads();
  for (int i = t; i < NB; i += 256)
    if (h[i]) atomicAdd(&bcnt[i], h[i]);
}

// Scan buckets: bbase (edge-record space), bcur=bbase.
// CSR space base is bbase[b] + 256*b (buckets before b are all full).
__global__ void k_bscan(const int* __restrict__ bcnt, int* __restrict__ bbase,
                        int* __restrict__ bcur) {
  __shared__ int s[256];
  int t = threadIdx.x;
  s[t] = (t < NB) ? bcnt[t] : 0; __syncthreads();
  for (int off = 1; off < 256; off <<= 1) {
    int x = s[t];
    int y = (t >= off) ? s[t - off] : 0;
    __syncthreads();
    s[t] = x + y; __syncthreads();
  }
  if (t < NB) {
    int ex = (t == 0) ? 0 : s[t - 1];
    bbase[t] = ex;
    bcur[t] = ex;
  }
}

__global__ __launch_bounds__(256) void k_bfill(const void* ei, int E,
    int* __restrict__ bcur, u32* __restrict__ recs, const int* flag) {
  __shared__ int h[NB];
  __shared__ int lbase[NB];
  __shared__ int lcur[NB];
  int is64 = *flag;
  int t = threadIdx.x;
  for (int i = t; i < NB; i += 256) h[i] = 0;
  __syncthreads();
  u32 rr[16];
  int bb[16];
  long long base = (long long)blockIdx.x * EPB + t * 16;
#pragma unroll
  for (int j = 0; j < 16; ++j) {
    long long e = base + j;
    if (e < E) {
      int s = load_idx(ei, e, is64);
      int d = load_idx(ei, (long long)E + e, is64);
      int b = d >> 8;
      rr[j] = ((u32)s << 8) | (u32)(d & 255);
      bb[j] = b;
      atomicAdd(&h[b], 1);
    } else bb[j] = -1;
  }
  __syncthreads();
  for (int i = t; i < NB; i += 256) {
    lbase[i] = h[i] ? atomicAdd(&bcur[i], h[i]) : 0;
    lcur[i] = 0;
  }
  __syncthreads();
#pragma unroll
  for (int j = 0; j < 16; ++j) {
    if (bb[j] >= 0) {
      int loc = atomicAdd(&lcur[bb[j]], 1);
      recs[lbase[bb[j]] + loc] = rr[j];
    }
  }
}

__global__ __launch_bounds__(512) void k_degw(const u32* __restrict__ recs,
    const int* __restrict__ bbase, const int* __restrict__ bcnt,
    int* __restrict__ deg) {
  __shared__ int h[256];
  int b = blockIdx.x;
  int t = threadIdx.x;
  if (t < 256) h[t] = 0;
  __syncthreads();
  int rb = bbase[b], cnt = bcnt[b];
  for (int i = t; i < cnt; i += 512) atomicAdd(&h[recs[rb + i] & 255u], 1);
  __syncthreads();
  int node = b * 256 + t;
  if (t < 256 && node < NN) deg[node] = h[t];
}

// Intra-bucket exclusive scan of (deg+1) + dinv. Grid = NB blocks of 256.
__global__ void k_scan3(const int* __restrict__ deg, const int* __restrict__ bbase,
                        int* __restrict__ offs, float* __restrict__ dinv) {
  __shared__ int s[256];
  int t = threadIdx.x;
  int i = blockIdx.x * 256 + t;
  int v = (i < NN) ? (deg[i] + 1) : 0;
  s[t] = v; __syncthreads();
  for (int off = 1; off < 256; off <<= 1) {
    int x = s[t];
    int y = (t >= off) ? s[t - off] : 0;
    __syncthreads();
    s[t] = x + y; __syncthreads();
  }
  if (i < NN) {
    offs[i] = bbase[blockIdx.x] + blockIdx.x * 256 + s[t] - v;
    dinv[i] = rsqrtf((float)v);
  }
}

__global__ __launch_bounds__(512) void k_window(const u32* __restrict__ recs,
    const int* __restrict__ bbase, const int* __restrict__ bcnt,
    const int* __restrict__ offs, u16* __restrict__ csr_s) {
  __shared__ u16 stage[WCAP];
  __shared__ int wcur[256];
  __shared__ int woff[256];
  __shared__ int info[1];
  int b = blockIdx.x;
  int t = threadIdx.x;
  int nodeBase = b * 256;
  int nin = min(256, NN - nodeBase);
  if (t == 0) info[0] = offs[nodeBase];
  __syncthreads();
  int gbase = info[0];
  if (t < 256) {
    if (t < nin) {
      woff[t] = offs[nodeBase + t] - gbase;
      wcur[t] = 0;
    } else { woff[t] = 0; wcur[t] = 0; }
  }
  __syncthreads();
  int rb = bbase[b], cnt = bcnt[b];
  int winsize = cnt + nin;
  bool ovf = winsize > WCAP;
  if (!ovf) {
    for (int i = t; i < cnt; i += 512) {
      u32 r = recs[rb + i];
      int d = r & 255u;
      int loc = atomicAdd(&wcur[d], 1);
      stage[woff[d] + loc] = (u16)(r >> 8);
    }
    __syncthreads();
    if (t < nin) stage[woff[t] + wcur[t]] = (u16)(nodeBase + t);
    __syncthreads();
    for (int i = t; i < winsize; i += 512) csr_s[gbase + i] = stage[i];
  } else {
    for (int i = t; i < cnt; i += 512) {
      u32 r = recs[rb + i];
      int d = r & 255u;
      int loc = atomicAdd(&wcur[d], 1);
      csr_s[gbase + woff[d] + loc] = (u16)(r >> 8);
    }
    __syncthreads();
    if (t < nin) csr_s[gbase + woff[t] + wcur[t]] = (u16)(nodeBase + t);
  }
}

// Prep: Vb = bf16(dinv[row]*V), W1/W2 transpose+cast. Needs dinv ready.
__global__ void k_prep(const float* __restrict__ V, const float* __restrict__ W1,
                       const float* __restrict__ W2, const float* __restrict__ dinv,
                       u16* __restrict__ Vb, u16* __restrict__ W1t,
                       u16* __restrict__ W2t) {
  int b = blockIdx.x;
  if (b < CAST_BLK) {
    int i = (b * 256 + threadIdx.x) * 4;
    float dv = dinv[i >> 7];
    float4 v = *(const float4*)(V + i);
    ushort4 o;
    o.x = f2bf(v.x * dv); o.y = f2bf(v.y * dv);
    o.z = f2bf(v.z * dv); o.w = f2bf(v.w * dv);
    *(ushort4*)(Vb + i) = o;
  } else if (b < CAST_BLK + WT1_BLK) {
    int i = (b - CAST_BLK) * 256 + threadIdx.x;
    int k = i >> 8, c = i & 255;
    W1t[c * DIN + k] = f2bf(W1[i]);
  } else {
    int i = (b - CAST_BLK - WT1_BLK) * 256 + threadIdx.x;
    int k = i >> 8, c = i & 255;
    W2t[c * DH + k] = f2bf(W2[i]);
  }
}

// Pure gather-sum aggregation (weights pre-folded into rows), 16-lane groups,
// 4 edges/iter, 1-deep software pipeline. out = dinv[node] * sum(rows).
template <int D>
__global__ __launch_bounds__(256) void k_agg(const u16* __restrict__ in,
    const int* __restrict__ offs, const int* __restrict__ deg,
    const u16* __restrict__ csr_s, const float* __restrict__ dinv,
    u16* __restrict__ out) {
  int node = (blockIdx.x * 256 + threadIdx.x) >> 6;
  int lane = threadIdx.x & 63;
  if (node >= NN) return;
  int beg = offs[node];
  int end = beg + deg[node] + 1;
  float dinvn = dinv[node];
  constexpr int CPL = D / 16;  // 8 or 16 channels per lane
  int grp = lane >> 4, sub = lane & 15;
  float acc[CPL] = {};
  int e = beg + grp;
  bool v0 = e < end;
  uint4 a0 = {0, 0, 0, 0}, b0 = {0, 0, 0, 0};
  if (v0) {
    const u16* r = in + (size_t)csr_s[e] * D + sub * CPL;
    a0 = *(const uint4*)r;
    if (D == 256) b0 = *(const uint4*)(r + 8);
  }
  while (v0) {
    int e1 = e + 4;
    bool v1 = e1 < end;
    uint4 a1 = {0, 0, 0, 0}, b1 = {0, 0, 0, 0};
    if (v1) {
      const u16* r = in + (size_t)csr_s[e1] * D + sub * CPL;
      a1 = *(const uint4*)r;
      if (D == 256) b1 = *(const uint4*)(r + 8);
    }
    {
      u32 w[4] = {a0.x, a0.y, a0.z, a0.w};
#pragma unroll
      for (int j = 0; j < 4; ++j) {
        acc[2 * j + 0] += bflo(w[j]);
        acc[2 * j + 1] += bfhi(w[j]);
      }
      if (D == 256) {
        u32 w2[4] = {b0.x, b0.y, b0.z, b0.w};
#pragma unroll
        for (int j = 0; j < 4; ++j) {
          acc[8 + 2 * j + 0] += bflo(w2[j]);
          acc[8 + 2 * j + 1] += bfhi(w2[j]);
        }
      }
    }
    e = e1; v0 = v1; a0 = a1; b0 = b1;
  }
#pragma unroll
  for (int j = 0; j < CPL; ++j) {
    acc[j] += __shfl_xor(acc[j], 16, 64);
    acc[j] += __shfl_xor(acc[j], 32, 64);
  }
  if (lane < 16) {
    u16* op = out + (size_t)node * D + sub * CPL;
#pragma unroll
    for (int q = 0; q < CPL / 4; ++q) {
      ushort4 o;
      o.x = f2bf(acc[4 * q + 0] * dinvn);
      o.y = f2bf(acc[4 * q + 1] * dinvn);
      o.z = f2bf(acc[4 * q + 2] * dinvn);
      o.w = f2bf(acc[4 * q + 3] * dinvn);
      *(ushort4*)(op + 4 * q) = o;
    }
  }
}

__global__ __launch_bounds__(256) void k_mgemm(const u16* __restrict__ A,
    const u16* __restrict__ Bt, const float* __restrict__ bias,
    u16* __restrict__ out, int M, int K,
    float* __restrict__ sums, float* __restrict__ sumsq) {
  __shared__ __align__(16) u16 As[128 * 32];
  __shared__ __align__(16) u16 Bs[128 * 32];
  int t = threadIdx.x;
  int l = t & 63;
  int w = t >> 6;
  int rowBase = blockIdx.x * 128;
  int colBase = blockIdx.y * 128;
  int wr = (w >> 1) * 64, wc = (w & 1) * 64;
  int rsel = l & 15, ksel = (l >> 4) * 8;

  f32x4 acc[4][4];
#pragma unroll
  for (int mi = 0; mi < 4; ++mi)
#pragma unroll
    for (int ni = 0; ni < 4; ++ni) acc[mi][ni] = (f32x4){0.f, 0.f, 0.f, 0.f};

  for (int k0 = 0; k0 < K; k0 += 32) {
#pragma unroll
    for (int c = 0; c < 2; ++c) {
      int idx = c * 256 + t;
      int row = idx >> 2;
      int kq = idx & 3;
      const u16* ga = A + (size_t)(rowBase + row) * K + k0 + kq * 8;
      const u16* gb = Bt + (size_t)(colBase + row) * K + k0 + kq * 8;
      __builtin_amdgcn_global_load_lds(
          (const __attribute__((address_space(1))) void*)ga,
          (__attribute__((address_space(3))) void*)(&As[idx * 8]), 16, 0, 0);
      __builtin_amdgcn_global_load_lds(
          (const __attribute__((address_space(1))) void*)gb,
          (__attribute__((address_space(3))) void*)(&Bs[idx * 8]), 16, 0, 0);
    }
    __syncthreads();
    short8 a[4], b[4];
#pragma unroll
    for (int mi = 0; mi < 4; ++mi)
      a[mi] = *(const short8*)(&As[(wr + mi * 16 + rsel) * 32 + ksel]);
#pragma unroll
    for (int ni = 0; ni < 4; ++ni)
      b[ni] = *(const short8*)(&Bs[(wc + ni * 16 + rsel) * 32 + ksel]);
#pragma unroll
    for (int mi = 0; mi < 4; ++mi)
#pragma unroll
      for (int ni = 0; ni < 4; ++ni)
        acc[mi][ni] = __builtin_amdgcn_mfma_f32_16x16x32_bf16(a[mi], b[ni], acc[mi][ni], 0, 0, 0);
    __syncthreads();
  }

#pragma unroll
  for (int ni = 0; ni < 4; ++ni) {
    int col = colBase + wc + ni * 16 + (l & 15);
    float bcol = bias[col];
    float s1 = 0.f, s2 = 0.f;
#pragma unroll
    for (int mi = 0; mi < 4; ++mi) {
#pragma unroll
      for (int r = 0; r < 4; ++r) {
        int row = rowBase + wr + mi * 16 + (l >> 4) * 4 + r;
        if (row < M) {
          float v = acc[mi][ni][r] + bcol;
          s1 += v; s2 += v * v;
          out[(size_t)row * 256 + col] = f2bf(v);
        }
      }
    }
    s1 += __shfl_xor(s1, 16, 64); s1 += __shfl_xor(s1, 32, 64);
    s2 += __shfl_xor(s2, 16, 64); s2 += __shfl_xor(s2, 32, 64);
    if (l < 16) {
      atomicAdd(&sums[col], s1);
      atomicAdd(&sumsq[col], s2);
    }
  }
}

__global__ void k_scale(const float* __restrict__ sum, const float* __restrict__ sumsq,
                        const float* __restrict__ g, const float* __restrict__ be,
                        float* __restrict__ scale, float* __restrict__ shift) {
  int c = threadIdx.x;
  float mean = sum[c] / (float)NN;
  float var = sumsq[c] / (float)NN - mean * mean;
  float sc = g[c] * rsqrtf(var + BN_EPS);
  scale[c] = sc;
  shift[c] = be[c] - mean * sc;
}

// h1n = bf16( relu(h*scl+sft) * dinv[row] ) — once per element, dinv folded.
__global__ __launch_bounds__(256) void k_normcast(const u16* __restrict__ h,
    const float* __restrict__ scale, const float* __restrict__ shift,
    const float* __restrict__ dinv, u16* __restrict__ y) {
  long long i = ((long long)blockIdx.x * 256 + threadIdx.x) * 8;
  int row = (int)(i >> 8);
  float dv = dinv[row];
  int c = (int)(i & 255);
  ushort4 v0 = *(const ushort4*)(h + i);
  ushort4 v1 = *(const ushort4*)(h + i + 4);
  ushort4 o0, o1;
  o0.x = f2bf(fmaxf(bf2f(v0.x) * scale[c + 0] + shift[c + 0], 0.f) * dv);
  o0.y = f2bf(fmaxf(bf2f(v0.y) * scale[c + 1] + shift[c + 1], 0.f) * dv);
  o0.z = f2bf(fmaxf(bf2f(v0.z) * scale[c + 2] + shift[c + 2], 0.f) * dv);
  o0.w = f2bf(fmaxf(bf2f(v0.w) * scale[c + 3] + shift[c + 3], 0.f) * dv);
  o1.x = f2bf(fmaxf(bf2f(v1.x) * scale[c + 4] + shift[c + 4], 0.f) * dv);
  o1.y = f2bf(fmaxf(bf2f(v1.y) * scale[c + 5] + shift[c + 5], 0.f) * dv);
  o1.z = f2bf(fmaxf(bf2f(v1.z) * scale[c + 6] + shift[c + 6], 0.f) * dv);
  o1.w = f2bf(fmaxf(bf2f(v1.w) * scale[c + 7] + shift[c + 7], 0.f) * dv);
  *(ushort4*)(y + i) = o0;
  *(ushort4*)(y + i + 4) = o1;
}

__global__ __launch_bounds__(256) void k_pool(const u16* __restrict__ h,
    const float* __restrict__ scale, const float* __restrict__ shift,
    const void* batch, float* __restrict__ Gsum, int* __restrict__ Gcnt,
    const int* flag) {
  int is64 = *flag;
  int c = threadIdx.x;
  int nodeBase = blockIdx.x * 64;
  float sc = scale[c], sh = shift[c];
  float local = 0.f;
  int cur = -1, len = 0;
  int nmax = min(64, NN - nodeBase);
  for (int r = 0; r < nmax; ++r) {
    int node = nodeBase + r;
    int b = load_idx(batch, node, is64);
    if (b != cur) {
      if (cur >= 0) {
        atomicAdd(&Gsum[(size_t)cur * 256 + c], local);
        if (c == 0) atomicAdd(&Gcnt[cur], len);
      }
      cur = b; local = 0.f; len = 0;
    }
    float v = bf2f(h[(size_t)node * 256 + c]) * sc + sh;
    local += fmaxf(v, 0.f);
    len++;
  }
  if (cur >= 0) {
    atomicAdd(&Gsum[(size_t)cur * 256 + c], local);
    if (c == 0) atomicAdd(&Gcnt[cur], len);
  }
}

__global__ __launch_bounds__(128) void k_fc(const float* __restrict__ Gsum,
    const int* __restrict__ Gcnt, const float* __restrict__ Wfc,
    const float* __restrict__ bfc, float* __restrict__ out) {
  int g = blockIdx.x, j = threadIdx.x;
  float inv = 1.0f / fmaxf((float)Gcnt[g], 1.0f);
  float acc = 0.f;
#pragma unroll 4
  for (int c = 0; c < 256; ++c) acc += Gsum[(size_t)g * 256 + c] * Wfc[c * 128 + j];
  out[(size_t)g * 128 + j] = acc * inv + bfc[j];
}

extern "C" void kernel_launch(void* const* d_in, const int* in_sizes, int n_in,
                              void* d_out, int out_size, void* d_ws, size_t ws_size,
                              hipStream_t stream) {
  const float* V   = (const float*)d_in[0];
  const void*  EI  = d_in[1];
  const void*  BAT = d_in[2];
  const float* W1  = (const float*)d_in[3];
  const float* b1  = (const float*)d_in[4];
  const float* g1  = (const float*)d_in[5];
  const float* be1 = (const float*)d_in[6];
  const float* W2  = (const float*)d_in[7];
  const float* b2  = (const float*)d_in[8];
  const float* g2  = (const float*)d_in[9];
  const float* be2 = (const float*)d_in[10];
  const float* Wfc = (const float*)d_in[11];
  const float* bfc = (const float*)d_in[12];
  float* out = (float*)d_out;
  const int E  = in_sizes[1] / 2;
  const int NE = E + NN;

  char* w = (char*)d_ws;
  size_t o = 0;
  auto alloc = [&](size_t bytes) -> char* {
    char* r = w + o;
    o = (o + bytes + 255) & ~(size_t)255;
    return r;
  };
  int*   flag   = (int*)alloc(4);
  int*   deg    = (int*)alloc((size_t)NN * 4);
  int*   offs   = (int*)alloc((size_t)NN * 4);
  int*   bcnt   = (int*)alloc(NB * 4);
  int*   bbase  = (int*)alloc(NB * 4);
  int*   bcur   = (int*)alloc(NB * 4);
  u32*   recs   = (u32*)alloc((size_t)E * 4);
  u16*   csr_s  = (u16*)alloc((size_t)NE * 2);
  float* dinv   = (float*)alloc((size_t)NN * 4);
  float* stats  = (float*)alloc(8 * 256 * 4);
  float *sums1 = stats, *sumsq1 = stats + 256, *sums2 = stats + 512, *sumsq2 = stats + 768;
  float *scale1 = stats + 1024, *shift1 = stats + 1280, *scale2 = stats + 1536, *shift2 = stats + 1792;
  float* Gsum   = (float*)alloc((size_t)NG * DH * 4);
  int*   Gcnt   = (int*)alloc(NG * 4);
  u16*   W1t    = (u16*)alloc((size_t)256 * DIN * 2);
  u16*   W2t    = (u16*)alloc((size_t)256 * DH * 2);
  u16*   Vb     = (u16*)alloc((size_t)NN * DIN * 2);
  u16*   agg1   = (u16*)alloc((size_t)NPAD * DIN * 2);
  u16*   h1b    = (u16*)alloc((size_t)NN * DH * 2);
  u16*   h1n    = (u16*)alloc((size_t)NN * DH * 2);
  u16*   agg2   = (u16*)alloc((size_t)NPAD * DH * 2);
  u16*   h2b    = (u16*)alloc((size_t)NN * DH * 2);
  (void)n_in; (void)out_size; (void)ws_size;

  hipMemsetAsync(bcnt, 0, NB * 4, stream);
  hipMemsetAsync(stats, 0, 4 * 256 * 4, stream);
  hipMemsetAsync(Gsum, 0, (size_t)NG * DH * 4, stream);
  hipMemsetAsync(Gcnt, 0, (size_t)NG * 4, stream);

  const int gB = (E + EPB - 1) / EPB;

  k_detect<<<1, 64, 0, stream>>>((const int*)EI, flag);
  k_bcnt<<<gB, 256, 0, stream>>>(EI, E, bcnt, flag);
  k_bscan<<<1, 256, 0, stream>>>(bcnt, bbase, bcur);
  k_bfill<<<gB, 256, 0, stream>>>(EI, E, bcur, recs, flag);
  k_degw<<<NB, 512, 0, stream>>>(recs, bbase, bcnt, deg);
  k_scan3<<<NB, 256, 0, stream>>>(deg, bbase, offs, dinv);
  k_window<<<NB, 512, 0, stream>>>(recs, bbase, bcnt, offs, csr_s);
  k_prep<<<CAST_BLK + WT1_BLK + WT2_BLK, 256, 0, stream>>>(V, W1, W2, dinv, Vb, W1t, W2t);

  k_agg<128><<<(NN + 3) / 4, 256, 0, stream>>>(Vb, offs, deg, csr_s, dinv, agg1);
  k_mgemm<<<dim3((NN + 127) / 128, 2), 256, 0, stream>>>(agg1, W1t, b1, h1b, NN, DIN,
                                                         sums1, sumsq1);
  k_scale<<<1, 256, 0, stream>>>(sums1, sumsq1, g1, be1, scale1, shift1);
  k_normcast<<<6250, 256, 0, stream>>>(h1b, scale1, shift1, dinv, h1n);

  k_agg<256><<<(NN + 3) / 4, 256, 0, stream>>>(h1n, offs, deg, csr_s, dinv, agg2);
  k_mgemm<<<dim3((NN + 127) / 128, 2), 256, 0, stream>>>(agg2, W2t, b2, h2b, NN, DH,
                                                         sums2, sumsq2);
  k_scale<<<1, 256, 0, stream>>>(sums2, sumsq2, g2, be2, scale2, shift2);

  k_pool<<<(NN + 63) / 64, 256, 0, stream>>>(h2b, scale2, shift2, BAT, Gsum, Gcnt, flag);
  k_fc<<<NG, 128, 0, stream>>>(Gsum, Gcnt, Wfc, bfc, out);
}

// Round 6
// 383.145 us; speedup vs baseline: 2.2528x; 1.0196x over previous
//
#include <hip/hip_runtime.h>
#include <stdint.h>

typedef unsigned int u32;
typedef unsigned short u16;
typedef __attribute__((ext_vector_type(8))) short short8;
typedef __attribute__((ext_vector_type(4))) float f32x4;

#define NN   50000
#define NPAD 50048
#define NG   512
#define DIN  128
#define DH   256
#define BN_EPS 1e-5f
#define NB   196          // coarse dst buckets of 256 nodes
#define EPB  4096         // edges per block in binning kernels
#define WCAP 24576        // LDS staging capacity (u16) per window
#define NT   8            // src tiles (6250 nodes = 3.2 MB of 256-wide bf16 rows)
#define TDIV 6250

#define CAST_BLK 6250
#define WT1_BLK  128
#define WT2_BLK  256

__device__ __forceinline__ float bf2f(u16 u) {
  union { u32 i; float f; } v; v.i = ((u32)u) << 16; return v.f;
}
__device__ __forceinline__ float bflo(u32 p) {
  union { u32 i; float f; } v; v.i = p << 16; return v.f;
}
__device__ __forceinline__ float bfhi(u32 p) {
  union { u32 i; float f; } v; v.i = p & 0xFFFF0000u; return v.f;
}
__device__ __forceinline__ u16 f2bf(float f) {
  union { float f; u32 i; } v; v.f = f;
  return (u16)((v.i + 0x7FFFu + ((v.i >> 16) & 1u)) >> 16);
}
__device__ __forceinline__ int load_idx(const void* p, long long i, int is64) {
  return is64 ? (int)((const long long*)p)[i] : ((const int*)p)[i];
}

__global__ void k_detect(const int* ei, int* flag) {
  if (threadIdx.x == 0 && blockIdx.x == 0) {
    int oddz = 0;
    for (int i = 0; i < 128; ++i) oddz += (ei[2 * i + 1] == 0) ? 1 : 0;
    *flag = (oddz == 128) ? 1 : 0;
  }
}

__global__ __launch_bounds__(256) void k_bcnt(const void* ei, int E,
    int* __restrict__ bcnt, const int* flag) {
  __shared__ int h[NB];
  int is64 = *flag;
  int t = threadIdx.x;
  for (int i = t; i < NB; i += 256) h[i] = 0;
  __syncthreads();
  long long base = (long long)blockIdx.x * EPB + t * 16;
#pragma unroll
  for (int j = 0; j < 16; ++j) {
    long long e = base + j;
    if (e < E) {
      int d = load_idx(ei, (long long)E + e, is64);
      atomicAdd(&h[d >> 8], 1);
    }
  }
  __syncthreads();
  for (int i = t; i < NB; i += 256)
    if (h[i]) atomicAdd(&bcnt[i], h[i]);
}

__global__ void k_bscan(const int* __restrict__ bcnt, int* __restrict__ bbase,
                        int* __restrict__ bcur) {
  __shared__ int s[256];
  int t = threadIdx.x;
  s[t] = (t < NB) ? bcnt[t] : 0; __syncthreads();
  for (int off = 1; off < 256; off <<= 1) {
    int x = s[t];
    int y = (t >= off) ? s[t - off] : 0;
    __syncthreads();
    s[t] = x + y; __syncthreads();
  }
  if (t < NB) {
    int ex = (t == 0) ? 0 : s[t - 1];
    bbase[t] = ex;
    bcur[t] = ex;
  }
}

__global__ __launch_bounds__(256) void k_bfill(const void* ei, int E,
    int* __restrict__ bcur, u32* __restrict__ recs, const int* flag) {
  __shared__ int h[NB];
  __shared__ int lbase[NB];
  __shared__ int lcur[NB];
  int is64 = *flag;
  int t = threadIdx.x;
  for (int i = t; i < NB; i += 256) h[i] = 0;
  __syncthreads();
  u32 rr[16];
  int bb[16];
  long long base = (long long)blockIdx.x * EPB + t * 16;
#pragma unroll
  for (int j = 0; j < 16; ++j) {
    long long e = base + j;
    if (e < E) {
      int s = load_idx(ei, e, is64);
      int d = load_idx(ei, (long long)E + e, is64);
      int b = d >> 8;
      rr[j] = ((u32)s << 8) | (u32)(d & 255);
      bb[j] = b;
      atomicAdd(&h[b], 1);
    } else bb[j] = -1;
  }
  __syncthreads();
  for (int i = t; i < NB; i += 256) {
    lbase[i] = h[i] ? atomicAdd(&bcur[i], h[i]) : 0;
    lcur[i] = 0;
  }
  __syncthreads();
#pragma unroll
  for (int j = 0; j < 16; ++j) {
    if (bb[j] >= 0) {
      int loc = atomicAdd(&lcur[bb[j]], 1);
      recs[lbase[bb[j]] + loc] = rr[j];
    }
  }
}

// Fused: per-(node,src-tile) histogram -> deg/offs/dinv -> tile-sorted CSR
// window staged in LDS, flushed contiguously. One block per dst bucket.
__global__ __launch_bounds__(512) void k_build(const u32* __restrict__ recs,
    const int* __restrict__ bbase, const int* __restrict__ bcnt,
    int* __restrict__ deg, int* __restrict__ offs, float* __restrict__ dinv,
    u16* __restrict__ csr_s) {
  __shared__ u32 cnt2[256][NT];   // counts, then per-(node,tile) offsets
  __shared__ int woff[256];
  __shared__ int sscan[256];
  __shared__ u16 stage[WCAP];
  int b = blockIdx.x;
  int t = threadIdx.x;
  int nodeBase = b * 256;
  int nin = min(256, NN - nodeBase);
  for (int i = t; i < 256 * NT; i += 512) ((u32*)cnt2)[i] = 0;
  __syncthreads();
  int rb = bbase[b], cnt = bcnt[b];
  for (int i = t; i < cnt; i += 512) {
    u32 r = recs[rb + i];
    atomicAdd(&cnt2[r & 255u][(r >> 8) / TDIV], 1u);
  }
  __syncthreads();
  // per-node: add self-loop to its tile, tile-prefix, total slots
  int slots = 0;
  if (t < nin) {
    cnt2[t][(u32)(nodeBase + t) / TDIV] += 1u;
    u32 run = 0;
#pragma unroll
    for (int k = 0; k < NT; ++k) { u32 c = cnt2[t][k]; cnt2[t][k] = run; run += c; }
    slots = (int)run;             // deg + 1
  }
  if (t < 256) sscan[t] = slots;
  __syncthreads();
  for (int off = 1; off < 256; off <<= 1) {
    int x = (t < 256) ? sscan[t] : 0;
    int y = (t >= off && t < 256) ? sscan[t - off] : 0;
    __syncthreads();
    if (t < 256) sscan[t] = x + y;
    __syncthreads();
  }
  int gbase = rb + nodeBase;      // CSR base of bucket (all prior buckets full)
  if (t < nin) {
    int ex = sscan[t] - slots;
    woff[t] = ex;
    offs[nodeBase + t] = gbase + ex;
    deg[nodeBase + t] = slots - 1;
    dinv[nodeBase + t] = rsqrtf((float)slots);
  }
  __syncthreads();
  int winsize = cnt + nin;
  if (winsize <= WCAP) {
    for (int i = t; i < cnt; i += 512) {
      u32 r = recs[rb + i];
      int d = r & 255u;
      u32 src = r >> 8;
      int loc = (int)atomicAdd(&cnt2[d][src / TDIV], 1u);
      stage[woff[d] + loc] = (u16)src;
    }
    if (t < nin) {      // self-loop record, atomic-shared with record fill
      int loc = (int)atomicAdd(&cnt2[t][(u32)(nodeBase + t) / TDIV], 1u);
      stage[woff[t] + loc] = (u16)(nodeBase + t);
    }
    __syncthreads();
    for (int i = t; i < winsize; i += 512) csr_s[gbase + i] = stage[i];
  } else {
    for (int i = t; i < cnt; i += 512) {
      u32 r = recs[rb + i];
      int d = r & 255u;
      u32 src = r >> 8;
      int loc = (int)atomicAdd(&cnt2[d][src / TDIV], 1u);
      csr_s[gbase + woff[d] + loc] = (u16)src;
    }
    if (t < nin) {
      int loc = (int)atomicAdd(&cnt2[t][(u32)(nodeBase + t) / TDIV], 1u);
      csr_s[gbase + woff[t] + loc] = (u16)(nodeBase + t);
    }
  }
}

// Prep: Vb = bf16(dinv[row]*V), W1/W2 transpose+cast.
__global__ void k_prep(const float* __restrict__ V, const float* __restrict__ W1,
                       const float* __restrict__ W2, const float* __restrict__ dinv,
                       u16* __restrict__ Vb, u16* __restrict__ W1t,
                       u16* __restrict__ W2t) {
  int b = blockIdx.x;
  if (b < CAST_BLK) {
    int i = (b * 256 + threadIdx.x) * 4;
    float dv = dinv[i >> 7];
    float4 v = *(const float4*)(V + i);
    ushort4 o;
    o.x = f2bf(v.x * dv); o.y = f2bf(v.y * dv);
    o.z = f2bf(v.z * dv); o.w = f2bf(v.w * dv);
    *(ushort4*)(Vb + i) = o;
  } else if (b < CAST_BLK + WT1_BLK) {
    int i = (b - CAST_BLK) * 256 + threadIdx.x;
    int k = i >> 8, c = i & 255;
    W1t[c * DIN + k] = f2bf(W1[i]);
  } else {
    int i = (b - CAST_BLK - WT1_BLK) * 256 + threadIdx.x;
    int k = i >> 8, c = i & 255;
    W2t[c * DH + k] = f2bf(W2[i]);
  }
}

// Pure gather-sum aggregation, 16-lane groups, 4 edges/iter, 1-deep pipeline.
// Edge lists are src-tile-sorted for L2 locality. out = dinv[node]*sum(rows).
template <int D>
__global__ __launch_bounds__(256) void k_agg(const u16* __restrict__ in,
    const int* __restrict__ offs, const int* __restrict__ deg,
    const u16* __restrict__ csr_s, const float* __restrict__ dinv,
    u16* __restrict__ out) {
  int node = (blockIdx.x * 256 + threadIdx.x) >> 6;
  int lane = threadIdx.x & 63;
  if (node >= NN) return;
  int beg = offs[node];
  int end = beg + deg[node] + 1;
  float dinvn = dinv[node];
  constexpr int CPL = D / 16;
  int grp = lane >> 4, sub = lane & 15;
  float acc[CPL] = {};
  int e = beg + grp;
  bool v0 = e < end;
  uint4 a0 = {0, 0, 0, 0}, b0 = {0, 0, 0, 0};
  if (v0) {
    const u16* r = in + (size_t)csr_s[e] * D + sub * CPL;
    a0 = *(const uint4*)r;
    if (D == 256) b0 = *(const uint4*)(r + 8);
  }
  while (v0) {
    int e1 = e + 4;
    bool v1 = e1 < end;
    uint4 a1 = {0, 0, 0, 0}, b1 = {0, 0, 0, 0};
    if (v1) {
      const u16* r = in + (size_t)csr_s[e1] * D + sub * CPL;
      a1 = *(const uint4*)r;
      if (D == 256) b1 = *(const uint4*)(r + 8);
    }
    {
      u32 w[4] = {a0.x, a0.y, a0.z, a0.w};
#pragma unroll
      for (int j = 0; j < 4; ++j) {
        acc[2 * j + 0] += bflo(w[j]);
        acc[2 * j + 1] += bfhi(w[j]);
      }
      if (D == 256) {
        u32 w2[4] = {b0.x, b0.y, b0.z, b0.w};
#pragma unroll
        for (int j = 0; j < 4; ++j) {
          acc[8 + 2 * j + 0] += bflo(w2[j]);
          acc[8 + 2 * j + 1] += bfhi(w2[j]);
        }
      }
    }
    e = e1; v0 = v1; a0 = a1; b0 = b1;
  }
#pragma unroll
  for (int j = 0; j < CPL; ++j) {
    acc[j] += __shfl_xor(acc[j], 16, 64);
    acc[j] += __shfl_xor(acc[j], 32, 64);
  }
  if (lane < 16) {
    u16* op = out + (size_t)node * D + sub * CPL;
#pragma unroll
    for (int q = 0; q < CPL / 4; ++q) {
      ushort4 o;
      o.x = f2bf(acc[4 * q + 0] * dinvn);
      o.y = f2bf(acc[4 * q + 1] * dinvn);
      o.z = f2bf(acc[4 * q + 2] * dinvn);
      o.w = f2bf(acc[4 * q + 3] * dinvn);
      *(ushort4*)(op + 4 * q) = o;
    }
  }
}

__global__ __launch_bounds__(256) void k_mgemm(const u16* __restrict__ A,
    const u16* __restrict__ Bt, const float* __restrict__ bias,
    u16* __restrict__ out, int M, int K,
    float* __restrict__ sums, float* __restrict__ sumsq) {
  __shared__ __align__(16) u16 As[128 * 32];
  __shared__ __align__(16) u16 Bs[128 * 32];
  int t = threadIdx.x;
  int l = t & 63;
  int w = t >> 6;
  int rowBase = blockIdx.x * 128;
  int colBase = blockIdx.y * 128;
  int wr = (w >> 1) * 64, wc = (w & 1) * 64;
  int rsel = l & 15, ksel = (l >> 4) * 8;

  f32x4 acc[4][4];
#pragma unroll
  for (int mi = 0; mi < 4; ++mi)
#pragma unroll
    for (int ni = 0; ni < 4; ++ni) acc[mi][ni] = (f32x4){0.f, 0.f, 0.f, 0.f};

  for (int k0 = 0; k0 < K; k0 += 32) {
#pragma unroll
    for (int c = 0; c < 2; ++c) {
      int idx = c * 256 + t;
      int row = idx >> 2;
      int kq = idx & 3;
      const u16* ga = A + (size_t)(rowBase + row) * K + k0 + kq * 8;
      const u16* gb = Bt + (size_t)(colBase + row) * K + k0 + kq * 8;
      __builtin_amdgcn_global_load_lds(
          (const __attribute__((address_space(1))) void*)ga,
          (__attribute__((address_space(3))) void*)(&As[idx * 8]), 16, 0, 0);
      __builtin_amdgcn_global_load_lds(
          (const __attribute__((address_space(1))) void*)gb,
          (__attribute__((address_space(3))) void*)(&Bs[idx * 8]), 16, 0, 0);
    }
    __syncthreads();
    short8 a[4], b[4];
#pragma unroll
    for (int mi = 0; mi < 4; ++mi)
      a[mi] = *(const short8*)(&As[(wr + mi * 16 + rsel) * 32 + ksel]);
#pragma unroll
    for (int ni = 0; ni < 4; ++ni)
      b[ni] = *(const short8*)(&Bs[(wc + ni * 16 + rsel) * 32 + ksel]);
#pragma unroll
    for (int mi = 0; mi < 4; ++mi)
#pragma unroll
      for (int ni = 0; ni < 4; ++ni)
        acc[mi][ni] = __builtin_amdgcn_mfma_f32_16x16x32_bf16(a[mi], b[ni], acc[mi][ni], 0, 0, 0);
    __syncthreads();
  }

#pragma unroll
  for (int ni = 0; ni < 4; ++ni) {
    int col = colBase + wc + ni * 16 + (l & 15);
    float bcol = bias[col];
    float s1 = 0.f, s2 = 0.f;
#pragma unroll
    for (int mi = 0; mi < 4; ++mi) {
#pragma unroll
      for (int r = 0; r < 4; ++r) {
        int row = rowBase + wr + mi * 16 + (l >> 4) * 4 + r;
        if (row < M) {
          float v = acc[mi][ni][r] + bcol;
          s1 += v; s2 += v * v;
          out[(size_t)row * 256 + col] = f2bf(v);
        }
      }
    }
    s1 += __shfl_xor(s1, 16, 64); s1 += __shfl_xor(s1, 32, 64);
    s2 += __shfl_xor(s2, 16, 64); s2 += __shfl_xor(s2, 32, 64);
    if (l < 16) {
      atomicAdd(&sums[col], s1);
      atomicAdd(&sumsq[col], s2);
    }
  }
}

__global__ void k_scale(const float* __restrict__ sum, const float* __restrict__ sumsq,
                        const float* __restrict__ g, const float* __restrict__ be,
                        float* __restrict__ scale, float* __restrict__ shift) {
  int c = threadIdx.x;
  float mean = sum[c] / (float)NN;
  float var = sumsq[c] / (float)NN - mean * mean;
  float sc = g[c] * rsqrtf(var + BN_EPS);
  scale[c] = sc;
  shift[c] = be[c] - mean * sc;
}

__global__ __launch_bounds__(256) void k_normcast(const u16* __restrict__ h,
    const float* __restrict__ scale, const float* __restrict__ shift,
    const float* __restrict__ dinv, u16* __restrict__ y) {
  long long i = ((long long)blockIdx.x * 256 + threadIdx.x) * 8;
  int row = (int)(i >> 8);
  float dv = dinv[row];
  int c = (int)(i & 255);
  ushort4 v0 = *(const ushort4*)(h + i);
  ushort4 v1 = *(const ushort4*)(h + i + 4);
  ushort4 o0, o1;
  o0.x = f2bf(fmaxf(bf2f(v0.x) * scale[c + 0] + shift[c + 0], 0.f) * dv);
  o0.y = f2bf(fmaxf(bf2f(v0.y) * scale[c + 1] + shift[c + 1], 0.f) * dv);
  o0.z = f2bf(fmaxf(bf2f(v0.z) * scale[c + 2] + shift[c + 2], 0.f) * dv);
  o0.w = f2bf(fmaxf(bf2f(v0.w) * scale[c + 3] + shift[c + 3], 0.f) * dv);
  o1.x = f2bf(fmaxf(bf2f(v1.x) * scale[c + 4] + shift[c + 4], 0.f) * dv);
  o1.y = f2bf(fmaxf(bf2f(v1.y) * scale[c + 5] + shift[c + 5], 0.f) * dv);
  o1.z = f2bf(fmaxf(bf2f(v1.z) * scale[c + 6] + shift[c + 6], 0.f) * dv);
  o1.w = f2bf(fmaxf(bf2f(v1.w) * scale[c + 7] + shift[c + 7], 0.f) * dv);
  *(ushort4*)(y + i) = o0;
  *(ushort4*)(y + i + 4) = o1;
}

__global__ __launch_bounds__(256) void k_pool(const u16* __restrict__ h,
    const float* __restrict__ scale, const float* __restrict__ shift,
    const void* batch, float* __restrict__ Gsum, int* __restrict__ Gcnt,
    const int* flag) {
  int is64 = *flag;
  int c = threadIdx.x;
  int nodeBase = blockIdx.x * 64;
  float sc = scale[c], sh = shift[c];
  float local = 0.f;
  int cur = -1, len = 0;
  int nmax = min(64, NN - nodeBase);
  for (int r = 0; r < nmax; ++r) {
    int node = nodeBase + r;
    int b = load_idx(batch, node, is64);
    if (b != cur) {
      if (cur >= 0) {
        atomicAdd(&Gsum[(size_t)cur * 256 + c], local);
        if (c == 0) atomicAdd(&Gcnt[cur], len);
      }
      cur = b; local = 0.f; len = 0;
    }
    float v = bf2f(h[(size_t)node * 256 + c]) * sc + sh;
    local += fmaxf(v, 0.f);
    len++;
  }
  if (cur >= 0) {
    atomicAdd(&Gsum[(size_t)cur * 256 + c], local);
    if (c == 0) atomicAdd(&Gcnt[cur], len);
  }
}

__global__ __launch_bounds__(128) void k_fc(const float* __restrict__ Gsum,
    const int* __restrict__ Gcnt, const float* __restrict__ Wfc,
    const float* __restrict__ bfc, float* __restrict__ out) {
  int g = blockIdx.x, j = threadIdx.x;
  float inv = 1.0f / fmaxf((float)Gcnt[g], 1.0f);
  float acc = 0.f;
#pragma unroll 4
  for (int c = 0; c < 256; ++c) acc += Gsum[(size_t)g * 256 + c] * Wfc[c * 128 + j];
  out[(size_t)g * 128 + j] = acc * inv + bfc[j];
}

extern "C" void kernel_launch(void* const* d_in, const int* in_sizes, int n_in,
                              void* d_out, int out_size, void* d_ws, size_t ws_size,
                              hipStream_t stream) {
  const float* V   = (const float*)d_in[0];
  const void*  EI  = d_in[1];
  const void*  BAT = d_in[2];
  const float* W1  = (const float*)d_in[3];
  const float* b1  = (const float*)d_in[4];
  const float* g1  = (const float*)d_in[5];
  const float* be1 = (const float*)d_in[6];
  const float* W2  = (const float*)d_in[7];
  const float* b2  = (const float*)d_in[8];
  const float* g2  = (const float*)d_in[9];
  const float* be2 = (const float*)d_in[10];
  const float* Wfc = (const float*)d_in[11];
  const float* bfc = (const float*)d_in[12];
  float* out = (float*)d_out;
  const int E  = in_sizes[1] / 2;
  const int NE = E + NN;

  char* w = (char*)d_ws;
  size_t o = 0;
  auto alloc = [&](size_t bytes) -> char* {
    char* r = w + o;
    o = (o + bytes + 255) & ~(size_t)255;
    return r;
  };
  int*   flag   = (int*)alloc(4);
  int*   deg    = (int*)alloc((size_t)NN * 4);
  int*   offs   = (int*)alloc((size_t)NN * 4);
  int*   bcnt   = (int*)alloc(NB * 4);
  int*   bbase  = (int*)alloc(NB * 4);
  int*   bcur   = (int*)alloc(NB * 4);
  u32*   recs   = (u32*)alloc((size_t)E * 4);
  u16*   csr_s  = (u16*)alloc((size_t)NE * 2);
  float* dinv   = (float*)alloc((size_t)NN * 4);
  float* stats  = (float*)alloc(8 * 256 * 4);
  float *sums1 = stats, *sumsq1 = stats + 256, *sums2 = stats + 512, *sumsq2 = stats + 768;
  float *scale1 = stats + 1024, *shift1 = stats + 1280, *scale2 = stats + 1536, *shift2 = stats + 1792;
  float* Gsum   = (float*)alloc((size_t)NG * DH * 4);
  int*   Gcnt   = (int*)alloc(NG * 4);
  u16*   W1t    = (u16*)alloc((size_t)256 * DIN * 2);
  u16*   W2t    = (u16*)alloc((size_t)256 * DH * 2);
  u16*   Vb     = (u16*)alloc((size_t)NN * DIN * 2);
  u16*   agg1   = (u16*)alloc((size_t)NPAD * DIN * 2);
  u16*   h1b    = (u16*)alloc((size_t)NN * DH * 2);
  u16*   h1n    = (u16*)alloc((size_t)NN * DH * 2);
  u16*   agg2   = (u16*)alloc((size_t)NPAD * DH * 2);
  u16*   h2b    = (u16*)alloc((size_t)NN * DH * 2);
  (void)n_in; (void)out_size; (void)ws_size;

  hipMemsetAsync(bcnt, 0, NB * 4, stream);
  hipMemsetAsync(stats, 0, 4 * 256 * 4, stream);
  hipMemsetAsync(Gsum, 0, (size_t)NG * DH * 4, stream);
  hipMemsetAsync(Gcnt, 0, (size_t)NG * 4, stream);

  const int gB = (E + EPB - 1) / EPB;

  k_detect<<<1, 64, 0, stream>>>((const int*)EI, flag);
  k_bcnt<<<gB, 256, 0, stream>>>(EI, E, bcnt, flag);
  k_bscan<<<1, 256, 0, stream>>>(bcnt, bbase, bcur);
  k_bfill<<<gB, 256, 0, stream>>>(EI, E, bcur, recs, flag);
  k_build<<<NB, 512, 0, stream>>>(recs, bbase, bcnt, deg, offs, dinv, csr_s);
  k_prep<<<CAST_BLK + WT1_BLK + WT2_BLK, 256, 0, stream>>>(V, W1, W2, dinv, Vb, W1t, W2t);

  k_agg<128><<<(NN + 3) / 4, 256, 0, stream>>>(Vb, offs, deg, csr_s, dinv, agg1);
  k_mgemm<<<dim3((NN + 127) / 128, 2), 256, 0, stream>>>(agg1, W1t, b1, h1b, NN, DIN,
                                                         sums1, sumsq1);
  k_scale<<<1, 256, 0, stream>>>(sums1, sumsq1, g1, be1, scale1, shift1);
  k_normcast<<<6250, 256, 0, stream>>>(h1b, scale1, shift1, dinv, h1n);

  k_agg<256><<<(NN + 3) / 4, 256, 0, stream>>>(h1n, offs, deg, csr_s, dinv, agg2);
  k_mgemm<<<dim3((NN + 127) / 128, 2), 256, 0, stream>>>(agg2, W2t, b2, h2b, NN, DH,
                                                         sums2, sumsq2);
  k_scale<<<1, 256, 0, stream>>>(sums2, sumsq2, g2, be2, scale2, shift2);

  k_pool<<<(NN + 63) / 64, 256, 0, stream>>>(h2b, scale2, shift2, BAT, Gsum, Gcnt, flag);
  k_fc<<<NG, 128, 0, stream>>>(Gsum, Gcnt, Wfc, bfc, out);
}

// Round 7
// 336.920 us; speedup vs baseline: 2.5618x; 1.1372x over previous
//
#include <hip/hip_runtime.h>
#include <stdint.h>

typedef unsigned int u32;
typedef unsigned short u16;
typedef unsigned char u8;
typedef __attribute__((ext_vector_type(8))) short short8;
typedef __attribute__((ext_vector_type(4))) float f32x4;
typedef __attribute__((ext_vector_type(2))) float f32x2;

#if !__has_builtin(__builtin_amdgcn_cvt_pk_f32_fp8) || !__has_builtin(__builtin_amdgcn_cvt_pk_fp8_f32)
#include <hip/hip_fp8.h>
#define FP8_FALLBACK 1
#endif

#define NN   50000
#define NPAD 50048
#define NG   512
#define DIN  128
#define DH   256
#define BN_EPS 1e-5f
#define NB   196          // coarse dst buckets of 256 nodes
#define EPB  4096         // edges per block in binning kernels
#define WCAP 24576        // LDS staging capacity (u16) per window
#define NT   8            // src tiles for L2 locality
#define TDIV 6250

#define CAST_BLK 6250
#define WT1_BLK  128
#define WT2_BLK  256

__device__ __forceinline__ float bf2f(u16 u) {
  union { u32 i; float f; } v; v.i = ((u32)u) << 16; return v.f;
}
__device__ __forceinline__ float bflo(u32 p) {
  union { u32 i; float f; } v; v.i = p << 16; return v.f;
}
__device__ __forceinline__ float bfhi(u32 p) {
  union { u32 i; float f; } v; v.i = p & 0xFFFF0000u; return v.f;
}
__device__ __forceinline__ u16 f2bf(float f) {
  union { float f; u32 i; } v; v.f = f;
  return (u16)((v.i + 0x7FFFu + ((v.i >> 16) & 1u)) >> 16);
}
__device__ __forceinline__ int load_idx(const void* p, long long i, int is64) {
  return is64 ? (int)((const long long*)p)[i] : ((const int*)p)[i];
}

// ---- fp8 e4m3 (OCP) pack/unpack ----
__device__ __forceinline__ void fp8x4_dec(u32 w, float* o) {
#ifndef FP8_FALLBACK
  f32x2 lo = __builtin_amdgcn_cvt_pk_f32_fp8(w, false);
  f32x2 hi = __builtin_amdgcn_cvt_pk_f32_fp8(w, true);
  o[0] = lo.x; o[1] = lo.y; o[2] = hi.x; o[3] = hi.y;
#else
  __hip_fp8_e4m3 t;
#pragma unroll
  for (int k = 0; k < 4; ++k) { t.__x = (u8)(w >> (8 * k)); o[k] = (float)t; }
#endif
}
__device__ __forceinline__ u32 fp8x4_enc(float a, float b, float c, float d) {
#ifndef FP8_FALLBACK
  u32 r = 0;
  r = __builtin_amdgcn_cvt_pk_fp8_f32(a, b, r, false);
  r = __builtin_amdgcn_cvt_pk_fp8_f32(c, d, r, true);
  return r;
#else
  __hip_fp8_e4m3 qa(a), qb(b), qc(c), qd(d);
  return (u32)qa.__x | ((u32)qb.__x << 8) | ((u32)qc.__x << 16) | ((u32)qd.__x << 24);
#endif
}

__global__ void k_detect(const int* ei, int* flag) {
  if (threadIdx.x == 0 && blockIdx.x == 0) {
    int oddz = 0;
    for (int i = 0; i < 128; ++i) oddz += (ei[2 * i + 1] == 0) ? 1 : 0;
    *flag = (oddz == 128) ? 1 : 0;
  }
}

__global__ __launch_bounds__(256) void k_bcnt(const void* ei, int E,
    int* __restrict__ bcnt, const int* flag) {
  __shared__ int h[NB];
  int is64 = *flag;
  int t = threadIdx.x;
  for (int i = t; i < NB; i += 256) h[i] = 0;
  __syncthreads();
  long long base = (long long)blockIdx.x * EPB + t * 16;
#pragma unroll
  for (int j = 0; j < 16; ++j) {
    long long e = base + j;
    if (e < E) {
      int d = load_idx(ei, (long long)E + e, is64);
      atomicAdd(&h[d >> 8], 1);
    }
  }
  __syncthreads();
  for (int i = t; i < NB; i += 256)
    if (h[i]) atomicAdd(&bcnt[i], h[i]);
}

__global__ void k_bscan(const int* __restrict__ bcnt, int* __restrict__ bbase,
                        int* __restrict__ bcur) {
  __shared__ int s[256];
  int t = threadIdx.x;
  s[t] = (t < NB) ? bcnt[t] : 0; __syncthreads();
  for (int off = 1; off < 256; off <<= 1) {
    int x = s[t];
    int y = (t >= off) ? s[t - off] : 0;
    __syncthreads();
    s[t] = x + y; __syncthreads();
  }
  if (t < NB) {
    int ex = (t == 0) ? 0 : s[t - 1];
    bbase[t] = ex;
    bcur[t] = ex;
  }
}

__global__ __launch_bounds__(256) void k_bfill(const void* ei, int E,
    int* __restrict__ bcur, u32* __restrict__ recs, const int* flag) {
  __shared__ int h[NB];
  __shared__ int lbase[NB];
  __shared__ int lcur[NB];
  int is64 = *flag;
  int t = threadIdx.x;
  for (int i = t; i < NB; i += 256) h[i] = 0;
  __syncthreads();
  u32 rr[16];
  int bb[16];
  long long base = (long long)blockIdx.x * EPB + t * 16;
#pragma unroll
  for (int j = 0; j < 16; ++j) {
    long long e = base + j;
    if (e < E) {
      int s = load_idx(ei, e, is64);
      int d = load_idx(ei, (long long)E + e, is64);
      int b = d >> 8;
      rr[j] = ((u32)s << 8) | (u32)(d & 255);
      bb[j] = b;
      atomicAdd(&h[b], 1);
    } else bb[j] = -1;
  }
  __syncthreads();
  for (int i = t; i < NB; i += 256) {
    lbase[i] = h[i] ? atomicAdd(&bcur[i], h[i]) : 0;
    lcur[i] = 0;
  }
  __syncthreads();
#pragma unroll
  for (int j = 0; j < 16; ++j) {
    if (bb[j] >= 0) {
      int loc = atomicAdd(&lcur[bb[j]], 1);
      recs[lbase[bb[j]] + loc] = rr[j];
    }
  }
}

// Fused: per-(node,src-tile) histogram -> deg/offs/dinv -> tile-sorted CSR.
__global__ __launch_bounds__(512) void k_build(const u32* __restrict__ recs,
    const int* __restrict__ bbase, const int* __restrict__ bcnt,
    int* __restrict__ deg, int* __restrict__ offs, float* __restrict__ dinv,
    u16* __restrict__ csr_s) {
  __shared__ u32 cnt2[256][NT];
  __shared__ int woff[256];
  __shared__ int sscan[256];
  __shared__ u16 stage[WCAP];
  int b = blockIdx.x;
  int t = threadIdx.x;
  int nodeBase = b * 256;
  int nin = min(256, NN - nodeBase);
  for (int i = t; i < 256 * NT; i += 512) ((u32*)cnt2)[i] = 0;
  __syncthreads();
  int rb = bbase[b], cnt = bcnt[b];
  for (int i = t; i < cnt; i += 512) {
    u32 r = recs[rb + i];
    atomicAdd(&cnt2[r & 255u][(r >> 8) / TDIV], 1u);
  }
  __syncthreads();
  int slots = 0;
  if (t < nin) {
    cnt2[t][(u32)(nodeBase + t) / TDIV] += 1u;
    u32 run = 0;
#pragma unroll
    for (int k = 0; k < NT; ++k) { u32 c = cnt2[t][k]; cnt2[t][k] = run; run += c; }
    slots = (int)run;
  }
  if (t < 256) sscan[t] = slots;
  __syncthreads();
  for (int off = 1; off < 256; off <<= 1) {
    int x = (t < 256) ? sscan[t] : 0;
    int y = (t >= off && t < 256) ? sscan[t - off] : 0;
    __syncthreads();
    if (t < 256) sscan[t] = x + y;
    __syncthreads();
  }
  int gbase = rb + nodeBase;
  if (t < nin) {
    int ex = sscan[t] - slots;
    woff[t] = ex;
    offs[nodeBase + t] = gbase + ex;
    deg[nodeBase + t] = slots - 1;
    dinv[nodeBase + t] = rsqrtf((float)slots);
  }
  __syncthreads();
  int winsize = cnt + nin;
  if (winsize <= WCAP) {
    for (int i = t; i < cnt; i += 512) {
      u32 r = recs[rb + i];
      int d = r & 255u;
      u32 src = r >> 8;
      int loc = (int)atomicAdd(&cnt2[d][src / TDIV], 1u);
      stage[woff[d] + loc] = (u16)src;
    }
    if (t < nin) {
      int loc = (int)atomicAdd(&cnt2[t][(u32)(nodeBase + t) / TDIV], 1u);
      stage[woff[t] + loc] = (u16)(nodeBase + t);
    }
    __syncthreads();
    for (int i = t; i < winsize; i += 512) csr_s[gbase + i] = stage[i];
  } else {
    for (int i = t; i < cnt; i += 512) {
      u32 r = recs[rb + i];
      int d = r & 255u;
      u32 src = r >> 8;
      int loc = (int)atomicAdd(&cnt2[d][src / TDIV], 1u);
      csr_s[gbase + woff[d] + loc] = (u16)src;
    }
    if (t < nin) {
      int loc = (int)atomicAdd(&cnt2[t][(u32)(nodeBase + t) / TDIV], 1u);
      csr_s[gbase + woff[t] + loc] = (u16)(nodeBase + t);
    }
  }
}

__global__ void k_prep(const float* __restrict__ V, const float* __restrict__ W1,
                       const float* __restrict__ W2, const float* __restrict__ dinv,
                       u16* __restrict__ Vb, u16* __restrict__ W1t,
                       u16* __restrict__ W2t) {
  int b = blockIdx.x;
  if (b < CAST_BLK) {
    int i = (b * 256 + threadIdx.x) * 4;
    float dv = dinv[i >> 7];
    float4 v = *(const float4*)(V + i);
    ushort4 o;
    o.x = f2bf(v.x * dv); o.y = f2bf(v.y * dv);
    o.z = f2bf(v.z * dv); o.w = f2bf(v.w * dv);
    *(ushort4*)(Vb + i) = o;
  } else if (b < CAST_BLK + WT1_BLK) {
    int i = (b - CAST_BLK) * 256 + threadIdx.x;
    int k = i >> 8, c = i & 255;
    W1t[c * DIN + k] = f2bf(W1[i]);
  } else {
    int i = (b - CAST_BLK - WT1_BLK) * 256 + threadIdx.x;
    int k = i >> 8, c = i & 255;
    W2t[c * DH + k] = f2bf(W2[i]);
  }
}

// Layer-1 aggregation: bf16 rows [N,128], 16-lane groups, 4 edges/iter,
// depth-3 software pipeline. out = dinv[node]*sum(rows), bf16.
__global__ __launch_bounds__(256) void k_agg1(const u16* __restrict__ in,
    const int* __restrict__ offs, const int* __restrict__ deg,
    const u16* __restrict__ csr_s, const float* __restrict__ dinv,
    u16* __restrict__ out) {
  int node = (blockIdx.x * 256 + threadIdx.x) >> 6;
  int lane = threadIdx.x & 63;
  if (node >= NN) return;
  int beg = offs[node];
  int end = beg + deg[node] + 1;
  float dinvn = dinv[node];
  int grp = lane >> 4, sub = lane & 15;
  float acc[8] = {};
  int e = beg + grp;
  bool v0 = e < end, v1 = e + 4 < end, v2 = e + 8 < end;
  uint4 r0, r1, r2;
  if (v0) r0 = *((const uint4*)(in + (size_t)csr_s[e] * 128) + sub);
  if (v1) r1 = *((const uint4*)(in + (size_t)csr_s[e + 4] * 128) + sub);
  if (v2) r2 = *((const uint4*)(in + (size_t)csr_s[e + 8] * 128) + sub);
  e += 12;
  while (v0) {
    bool v3 = e < end;
    uint4 r3;
    if (v3) r3 = *((const uint4*)(in + (size_t)csr_s[e] * 128) + sub);
    {
      u32 w[4] = {r0.x, r0.y, r0.z, r0.w};
#pragma unroll
      for (int j = 0; j < 4; ++j) {
        acc[2 * j + 0] += bflo(w[j]);
        acc[2 * j + 1] += bfhi(w[j]);
      }
    }
    r0 = r1; r1 = r2; r2 = r3;
    v0 = v1; v1 = v2; v2 = v3;
    e += 4;
  }
#pragma unroll
  for (int j = 0; j < 8; ++j) {
    acc[j] += __shfl_xor(acc[j], 16, 64);
    acc[j] += __shfl_xor(acc[j], 32, 64);
  }
  if (lane < 16) {
    u16* op = out + (size_t)node * 128 + sub * 8;
#pragma unroll
    for (int q = 0; q < 2; ++q) {
      ushort4 o;
      o.x = f2bf(acc[4 * q + 0] * dinvn);
      o.y = f2bf(acc[4 * q + 1] * dinvn);
      o.z = f2bf(acc[4 * q + 2] * dinvn);
      o.w = f2bf(acc[4 * q + 3] * dinvn);
      *(ushort4*)(op + 4 * q) = o;
    }
  }
}

// Layer-2 aggregation: fp8 rows [N,256] (16B/lane covers 16 channels),
// depth-3 pipeline, bf16 output.
__global__ __launch_bounds__(256) void k_agg2(const u8* __restrict__ in,
    const int* __restrict__ offs, const int* __restrict__ deg,
    const u16* __restrict__ csr_s, const float* __restrict__ dinv,
    u16* __restrict__ out) {
  int node = (blockIdx.x * 256 + threadIdx.x) >> 6;
  int lane = threadIdx.x & 63;
  if (node >= NN) return;
  int beg = offs[node];
  int end = beg + deg[node] + 1;
  float dinvn = dinv[node];
  int grp = lane >> 4, sub = lane & 15;
  float acc[16] = {};
  int e = beg + grp;
  bool v0 = e < end, v1 = e + 4 < end, v2 = e + 8 < end;
  uint4 r0, r1, r2;
  if (v0) r0 = *((const uint4*)(in + (size_t)csr_s[e] * 256) + sub);
  if (v1) r1 = *((const uint4*)(in + (size_t)csr_s[e + 4] * 256) + sub);
  if (v2) r2 = *((const uint4*)(in + (size_t)csr_s[e + 8] * 256) + sub);
  e += 12;
  while (v0) {
    bool v3 = e < end;
    uint4 r3;
    if (v3) r3 = *((const uint4*)(in + (size_t)csr_s[e] * 256) + sub);
    {
      u32 w[4] = {r0.x, r0.y, r0.z, r0.w};
#pragma unroll
      for (int j = 0; j < 4; ++j) {
        float f[4];
        fp8x4_dec(w[j], f);
        acc[4 * j + 0] += f[0];
        acc[4 * j + 1] += f[1];
        acc[4 * j + 2] += f[2];
        acc[4 * j + 3] += f[3];
      }
    }
    r0 = r1; r1 = r2; r2 = r3;
    v0 = v1; v1 = v2; v2 = v3;
    e += 4;
  }
#pragma unroll
  for (int j = 0; j < 16; ++j) {
    acc[j] += __shfl_xor(acc[j], 16, 64);
    acc[j] += __shfl_xor(acc[j], 32, 64);
  }
  if (lane < 16) {
    u16* op = out + (size_t)node * 256 + sub * 16;
#pragma unroll
    for (int q = 0; q < 4; ++q) {
      ushort4 o;
      o.x = f2bf(acc[4 * q + 0] * dinvn);
      o.y = f2bf(acc[4 * q + 1] * dinvn);
      o.z = f2bf(acc[4 * q + 2] * dinvn);
      o.w = f2bf(acc[4 * q + 3] * dinvn);
      *(ushort4*)(op + 4 * q) = o;
    }
  }
}

__global__ __launch_bounds__(256) void k_mgemm(const u16* __restrict__ A,
    const u16* __restrict__ Bt, const float* __restrict__ bias,
    u16* __restrict__ out, int M, int K,
    float* __restrict__ sums, float* __restrict__ sumsq) {
  __shared__ __align__(16) u16 As[128 * 32];
  __shared__ __align__(16) u16 Bs[128 * 32];
  int t = threadIdx.x;
  int l = t & 63;
  int w = t >> 6;
  int rowBase = blockIdx.x * 128;
  int colBase = blockIdx.y * 128;
  int wr = (w >> 1) * 64, wc = (w & 1) * 64;
  int rsel = l & 15, ksel = (l >> 4) * 8;

  f32x4 acc[4][4];
#pragma unroll
  for (int mi = 0; mi < 4; ++mi)
#pragma unroll
    for (int ni = 0; ni < 4; ++ni) acc[mi][ni] = (f32x4){0.f, 0.f, 0.f, 0.f};

  for (int k0 = 0; k0 < K; k0 += 32) {
#pragma unroll
    for (int c = 0; c < 2; ++c) {
      int idx = c * 256 + t;
      int row = idx >> 2;
      int kq = idx & 3;
      const u16* ga = A + (size_t)(rowBase + row) * K + k0 + kq * 8;
      const u16* gb = Bt + (size_t)(colBase + row) * K + k0 + kq * 8;
      __builtin_amdgcn_global_load_lds(
          (const __attribute__((address_space(1))) void*)ga,
          (__attribute__((address_space(3))) void*)(&As[idx * 8]), 16, 0, 0);
      __builtin_amdgcn_global_load_lds(
          (const __attribute__((address_space(1))) void*)gb,
          (__attribute__((address_space(3))) void*)(&Bs[idx * 8]), 16, 0, 0);
    }
    __syncthreads();
    short8 a[4], b[4];
#pragma unroll
    for (int mi = 0; mi < 4; ++mi)
      a[mi] = *(const short8*)(&As[(wr + mi * 16 + rsel) * 32 + ksel]);
#pragma unroll
    for (int ni = 0; ni < 4; ++ni)
      b[ni] = *(const short8*)(&Bs[(wc + ni * 16 + rsel) * 32 + ksel]);
#pragma unroll
    for (int mi = 0; mi < 4; ++mi)
#pragma unroll
      for (int ni = 0; ni < 4; ++ni)
        acc[mi][ni] = __builtin_amdgcn_mfma_f32_16x16x32_bf16(a[mi], b[ni], acc[mi][ni], 0, 0, 0);
    __syncthreads();
  }

#pragma unroll
  for (int ni = 0; ni < 4; ++ni) {
    int col = colBase + wc + ni * 16 + (l & 15);
    float bcol = bias[col];
    float s1 = 0.f, s2 = 0.f;
#pragma unroll
    for (int mi = 0; mi < 4; ++mi) {
#pragma unroll
      for (int r = 0; r < 4; ++r) {
        int row = rowBase + wr + mi * 16 + (l >> 4) * 4 + r;
        if (row < M) {
          float v = acc[mi][ni][r] + bcol;
          s1 += v; s2 += v * v;
          out[(size_t)row * 256 + col] = f2bf(v);
        }
      }
    }
    s1 += __shfl_xor(s1, 16, 64); s1 += __shfl_xor(s1, 32, 64);
    s2 += __shfl_xor(s2, 16, 64); s2 += __shfl_xor(s2, 32, 64);
    if (l < 16) {
      atomicAdd(&sums[col], s1);
      atomicAdd(&sumsq[col], s2);
    }
  }
}

__global__ void k_scale(const float* __restrict__ sum, const float* __restrict__ sumsq,
                        const float* __restrict__ g, const float* __restrict__ be,
                        float* __restrict__ scale, float* __restrict__ shift) {
  int c = threadIdx.x;
  float mean = sum[c] / (float)NN;
  float var = sumsq[c] / (float)NN - mean * mean;
  float sc = g[c] * rsqrtf(var + BN_EPS);
  scale[c] = sc;
  shift[c] = be[c] - mean * sc;
}

// h1n8 = fp8( relu(h*scl+sft) * dinv[row] ) — 8 channels/thread -> uint2.
__global__ __launch_bounds__(256) void k_normcast(const u16* __restrict__ h,
    const float* __restrict__ scale, const float* __restrict__ shift,
    const float* __restrict__ dinv, u32* __restrict__ y) {
  long long i = ((long long)blockIdx.x * 256 + threadIdx.x) * 8;
  int row = (int)(i >> 8);
  float dv = dinv[row];
  int c = (int)(i & 255);
  ushort4 v0 = *(const ushort4*)(h + i);
  ushort4 v1 = *(const ushort4*)(h + i + 4);
  float f[8];
  f[0] = fmaxf(bf2f(v0.x) * scale[c + 0] + shift[c + 0], 0.f) * dv;
  f[1] = fmaxf(bf2f(v0.y) * scale[c + 1] + shift[c + 1], 0.f) * dv;
  f[2] = fmaxf(bf2f(v0.z) * scale[c + 2] + shift[c + 2], 0.f) * dv;
  f[3] = fmaxf(bf2f(v0.w) * scale[c + 3] + shift[c + 3], 0.f) * dv;
  f[4] = fmaxf(bf2f(v1.x) * scale[c + 4] + shift[c + 4], 0.f) * dv;
  f[5] = fmaxf(bf2f(v1.y) * scale[c + 5] + shift[c + 5], 0.f) * dv;
  f[6] = fmaxf(bf2f(v1.z) * scale[c + 6] + shift[c + 6], 0.f) * dv;
  f[7] = fmaxf(bf2f(v1.w) * scale[c + 7] + shift[c + 7], 0.f) * dv;
  uint2 o;
  o.x = fp8x4_enc(f[0], f[1], f[2], f[3]);
  o.y = fp8x4_enc(f[4], f[5], f[6], f[7]);
  *(uint2*)(y + (i >> 2)) = o;
}

__global__ __launch_bounds__(256) void k_pool(const u16* __restrict__ h,
    const float* __restrict__ scale, const float* __restrict__ shift,
    const void* batch, float* __restrict__ Gsum, int* __restrict__ Gcnt,
    const int* flag) {
  int is64 = *flag;
  int c = threadIdx.x;
  int nodeBase = blockIdx.x * 64;
  float sc = scale[c], sh = shift[c];
  float local = 0.f;
  int cur = -1, len = 0;
  int nmax = min(64, NN - nodeBase);
  for (int r = 0; r < nmax; ++r) {
    int node = nodeBase + r;
    int b = load_idx(batch, node, is64);
    if (b != cur) {
      if (cur >= 0) {
        atomicAdd(&Gsum[(size_t)cur * 256 + c], local);
        if (c == 0) atomicAdd(&Gcnt[cur], len);
      }
      cur = b; local = 0.f; len = 0;
    }
    float v = bf2f(h[(size_t)node * 256 + c]) * sc + sh;
    local += fmaxf(v, 0.f);
    len++;
  }
  if (cur >= 0) {
    atomicAdd(&Gsum[(size_t)cur * 256 + c], local);
    if (c == 0) atomicAdd(&Gcnt[cur], len);
  }
}

__global__ __launch_bounds__(128) void k_fc(const float* __restrict__ Gsum,
    const int* __restrict__ Gcnt, const float* __restrict__ Wfc,
    const float* __restrict__ bfc, float* __restrict__ out) {
  int g = blockIdx.x, j = threadIdx.x;
  float inv = 1.0f / fmaxf((float)Gcnt[g], 1.0f);
  float acc = 0.f;
#pragma unroll 4
  for (int c = 0; c < 256; ++c) acc += Gsum[(size_t)g * 256 + c] * Wfc[c * 128 + j];
  out[(size_t)g * 128 + j] = acc * inv + bfc[j];
}

extern "C" void kernel_launch(void* const* d_in, const int* in_sizes, int n_in,
                              void* d_out, int out_size, void* d_ws, size_t ws_size,
                              hipStream_t stream) {
  const float* V   = (const float*)d_in[0];
  const void*  EI  = d_in[1];
  const void*  BAT = d_in[2];
  const float* W1  = (const float*)d_in[3];
  const float* b1  = (const float*)d_in[4];
  const float* g1  = (const float*)d_in[5];
  const float* be1 = (const float*)d_in[6];
  const float* W2  = (const float*)d_in[7];
  const float* b2  = (const float*)d_in[8];
  const float* g2  = (const float*)d_in[9];
  const float* be2 = (const float*)d_in[10];
  const float* Wfc = (const float*)d_in[11];
  const float* bfc = (const float*)d_in[12];
  float* out = (float*)d_out;
  const int E  = in_sizes[1] / 2;
  const int NE = E + NN;

  char* w = (char*)d_ws;
  size_t o = 0;
  auto alloc = [&](size_t bytes) -> char* {
    char* r = w + o;
    o = (o + bytes + 255) & ~(size_t)255;
    return r;
  };
  int*   flag   = (int*)alloc(4);
  int*   deg    = (int*)alloc((size_t)NN * 4);
  int*   offs   = (int*)alloc((size_t)NN * 4);
  int*   bcnt   = (int*)alloc(NB * 4);
  int*   bbase  = (int*)alloc(NB * 4);
  int*   bcur   = (int*)alloc(NB * 4);
  u32*   recs   = (u32*)alloc((size_t)E * 4);
  u16*   csr_s  = (u16*)alloc((size_t)NE * 2);
  float* dinv   = (float*)alloc((size_t)NN * 4);
  float* stats  = (float*)alloc(8 * 256 * 4);
  float *sums1 = stats, *sumsq1 = stats + 256, *sums2 = stats + 512, *sumsq2 = stats + 768;
  float *scale1 = stats + 1024, *shift1 = stats + 1280, *scale2 = stats + 1536, *shift2 = stats + 1792;
  float* Gsum   = (float*)alloc((size_t)NG * DH * 4);
  int*   Gcnt   = (int*)alloc(NG * 4);
  u16*   W1t    = (u16*)alloc((size_t)256 * DIN * 2);
  u16*   W2t    = (u16*)alloc((size_t)256 * DH * 2);
  u16*   Vb     = (u16*)alloc((size_t)NN * DIN * 2);
  u16*   agg1   = (u16*)alloc((size_t)NPAD * DIN * 2);
  u16*   h1b    = (u16*)alloc((size_t)NN * DH * 2);
  u32*   h1n8   = (u32*)alloc((size_t)NN * DH);      // fp8 [N,256]
  u16*   agg2   = (u16*)alloc((size_t)NPAD * DH * 2);
  u16*   h2b    = (u16*)alloc((size_t)NN * DH * 2);
  (void)n_in; (void)out_size; (void)ws_size;

  hipMemsetAsync(bcnt, 0, NB * 4, stream);
  hipMemsetAsync(stats, 0, 4 * 256 * 4, stream);
  hipMemsetAsync(Gsum, 0, (size_t)NG * DH * 4, stream);
  hipMemsetAsync(Gcnt, 0, (size_t)NG * 4, stream);

  const int gB = (E + EPB - 1) / EPB;

  k_detect<<<1, 64, 0, stream>>>((const int*)EI, flag);
  k_bcnt<<<gB, 256, 0, stream>>>(EI, E, bcnt, flag);
  k_bscan<<<1, 256, 0, stream>>>(bcnt, bbase, bcur);
  k_bfill<<<gB, 256, 0, stream>>>(EI, E, bcur, recs, flag);
  k_build<<<NB, 512, 0, stream>>>(recs, bbase, bcnt, deg, offs, dinv, csr_s);
  k_prep<<<CAST_BLK + WT1_BLK + WT2_BLK, 256, 0, stream>>>(V, W1, W2, dinv, Vb, W1t, W2t);

  k_agg1<<<(NN + 3) / 4, 256, 0, stream>>>(Vb, offs, deg, csr_s, dinv, agg1);
  k_mgemm<<<dim3((NN + 127) / 128, 2), 256, 0, stream>>>(agg1, W1t, b1, h1b, NN, DIN,
                                                         sums1, sumsq1);
  k_scale<<<1, 256, 0, stream>>>(sums1, sumsq1, g1, be1, scale1, shift1);
  k_normcast<<<6250, 256, 0, stream>>>(h1b, scale1, shift1, dinv, h1n8);

  k_agg2<<<(NN + 3) / 4, 256, 0, stream>>>((const u8*)h1n8, offs, deg, csr_s, dinv, agg2);
  k_mgemm<<<dim3((NN + 127) / 128, 2), 256, 0, stream>>>(agg2, W2t, b2, h2b, NN, DH,
                                                         sums2, sumsq2);
  k_scale<<<1, 256, 0, stream>>>(sums2, sumsq2, g2, be2, scale2, shift2);

  k_pool<<<(NN + 63) / 64, 256, 0, stream>>>(h2b, scale2, shift2, BAT, Gsum, Gcnt, flag);
  k_fc<<<NG, 128, 0, stream>>>(Gsum, Gcnt, Wfc, bfc, out);
}

// Round 8
// 314.130 us; speedup vs baseline: 2.7477x; 1.0725x over previous
//
#include <hip/hip_runtime.h>
#include <stdint.h>

typedef unsigned int u32;
typedef unsigned short u16;
typedef unsigned char u8;
typedef __attribute__((ext_vector_type(8))) short short8;
typedef __attribute__((ext_vector_type(4))) float f32x4;
typedef __attribute__((ext_vector_type(2))) float f32x2;

#if !__has_builtin(__builtin_amdgcn_cvt_pk_f32_fp8) || !__has_builtin(__builtin_amdgcn_cvt_pk_fp8_f32)
#include <hip/hip_fp8.h>
#define FP8_FALLBACK 1
#endif

#define NN   50000
#define NPAD 50048
#define NG   512
#define DIN  128
#define DH   256
#define BN_EPS 1e-5f
#define NB   196          // coarse dst buckets of 256 nodes
#define EPB  4096         // edges per block in binning kernels
#define WCAP 16384        // LDS staging capacity (u16) per window
#define NT   16           // src tiles (3125 nodes: 0.8 MB fp8x256 / 0.4 MB fp8x128)
#define TDIV 3125

#define CAST_BLK 6250
#define WT1_BLK  128
#define WT2_BLK  256

__device__ __forceinline__ float bf2f(u16 u) {
  union { u32 i; float f; } v; v.i = ((u32)u) << 16; return v.f;
}
__device__ __forceinline__ u16 f2bf(float f) {
  union { float f; u32 i; } v; v.f = f;
  return (u16)((v.i + 0x7FFFu + ((v.i >> 16) & 1u)) >> 16);
}
__device__ __forceinline__ int load_idx(const void* p, long long i, int is64) {
  return is64 ? (int)((const long long*)p)[i] : ((const int*)p)[i];
}

// ---- fp8 e4m3 (OCP) pack/unpack ----
__device__ __forceinline__ void fp8x4_dec(u32 w, float* o) {
#ifndef FP8_FALLBACK
  f32x2 lo = __builtin_amdgcn_cvt_pk_f32_fp8(w, false);
  f32x2 hi = __builtin_amdgcn_cvt_pk_f32_fp8(w, true);
  o[0] = lo.x; o[1] = lo.y; o[2] = hi.x; o[3] = hi.y;
#else
  __hip_fp8_e4m3 t;
#pragma unroll
  for (int k = 0; k < 4; ++k) { t.__x = (u8)(w >> (8 * k)); o[k] = (float)t; }
#endif
}
__device__ __forceinline__ u32 fp8x4_enc(float a, float b, float c, float d) {
#ifndef FP8_FALLBACK
  u32 r = 0;
  r = __builtin_amdgcn_cvt_pk_fp8_f32(a, b, r, false);
  r = __builtin_amdgcn_cvt_pk_fp8_f32(c, d, r, true);
  return r;
#else
  __hip_fp8_e4m3 qa(a), qb(b), qc(c), qd(d);
  return (u32)qa.__x | ((u32)qb.__x << 8) | ((u32)qc.__x << 16) | ((u32)qd.__x << 24);
#endif
}

__global__ void k_detect(const int* ei, int* flag) {
  if (threadIdx.x == 0 && blockIdx.x == 0) {
    int oddz = 0;
    for (int i = 0; i < 128; ++i) oddz += (ei[2 * i + 1] == 0) ? 1 : 0;
    *flag = (oddz == 128) ? 1 : 0;
  }
}

__global__ __launch_bounds__(256) void k_bcnt(const void* ei, int E,
    int* __restrict__ bcnt, const int* flag) {
  __shared__ int h[NB];
  int is64 = *flag;
  int t = threadIdx.x;
  for (int i = t; i < NB; i += 256) h[i] = 0;
  __syncthreads();
  long long base = (long long)blockIdx.x * EPB + t * 16;
#pragma unroll
  for (int j = 0; j < 16; ++j) {
    long long e = base + j;
    if (e < E) {
      int d = load_idx(ei, (long long)E + e, is64);
      atomicAdd(&h[d >> 8], 1);
    }
  }
  __syncthreads();
  for (int i = t; i < NB; i += 256)
    if (h[i]) atomicAdd(&bcnt[i], h[i]);
}

__global__ void k_bscan(const int* __restrict__ bcnt, int* __restrict__ bbase,
                        int* __restrict__ bcur) {
  __shared__ int s[256];
  int t = threadIdx.x;
  s[t] = (t < NB) ? bcnt[t] : 0; __syncthreads();
  for (int off = 1; off < 256; off <<= 1) {
    int x = s[t];
    int y = (t >= off) ? s[t - off] : 0;
    __syncthreads();
    s[t] = x + y; __syncthreads();
  }
  if (t < NB) {
    int ex = (t == 0) ? 0 : s[t - 1];
    bbase[t] = ex;
    bcur[t] = ex;
  }
}

__global__ __launch_bounds__(256) void k_bfill(const void* ei, int E,
    int* __restrict__ bcur, u32* __restrict__ recs, const int* flag) {
  __shared__ int h[NB];
  __shared__ int lbase[NB];
  __shared__ int lcur[NB];
  int is64 = *flag;
  int t = threadIdx.x;
  for (int i = t; i < NB; i += 256) h[i] = 0;
  __syncthreads();
  u32 rr[16];
  int bb[16];
  long long base = (long long)blockIdx.x * EPB + t * 16;
#pragma unroll
  for (int j = 0; j < 16; ++j) {
    long long e = base + j;
    if (e < E) {
      int s = load_idx(ei, e, is64);
      int d = load_idx(ei, (long long)E + e, is64);
      int b = d >> 8;
      rr[j] = ((u32)s << 8) | (u32)(d & 255);
      bb[j] = b;
      atomicAdd(&h[b], 1);
    } else bb[j] = -1;
  }
  __syncthreads();
  for (int i = t; i < NB; i += 256) {
    lbase[i] = h[i] ? atomicAdd(&bcur[i], h[i]) : 0;
    lcur[i] = 0;
  }
  __syncthreads();
#pragma unroll
  for (int j = 0; j < 16; ++j) {
    if (bb[j] >= 0) {
      int loc = atomicAdd(&lcur[bb[j]], 1);
      recs[lbase[bb[j]] + loc] = rr[j];
    }
  }
}

// Fused: per-(node,src-tile) histogram -> deg/offs/dinv -> tile-sorted CSR.
__global__ __launch_bounds__(512) void k_build(const u32* __restrict__ recs,
    const int* __restrict__ bbase, const int* __restrict__ bcnt,
    int* __restrict__ deg, int* __restrict__ offs, float* __restrict__ dinv,
    u16* __restrict__ csr_s) {
  __shared__ u32 cnt2[256][NT];
  __shared__ int woff[256];
  __shared__ int sscan[256];
  __shared__ u16 stage[WCAP];
  int b = blockIdx.x;
  int t = threadIdx.x;
  int nodeBase = b * 256;
  int nin = min(256, NN - nodeBase);
  for (int i = t; i < 256 * NT; i += 512) ((u32*)cnt2)[i] = 0;
  __syncthreads();
  int rb = bbase[b], cnt = bcnt[b];
  for (int i = t; i < cnt; i += 512) {
    u32 r = recs[rb + i];
    atomicAdd(&cnt2[r & 255u][(r >> 8) / TDIV], 1u);
  }
  __syncthreads();
  int slots = 0;
  if (t < nin) {
    cnt2[t][(u32)(nodeBase + t) / TDIV] += 1u;
    u32 run = 0;
#pragma unroll
    for (int k = 0; k < NT; ++k) { u32 c = cnt2[t][k]; cnt2[t][k] = run; run += c; }
    slots = (int)run;
  }
  if (t < 256) sscan[t] = slots;
  __syncthreads();
  for (int off = 1; off < 256; off <<= 1) {
    int x = (t < 256) ? sscan[t] : 0;
    int y = (t >= off && t < 256) ? sscan[t - off] : 0;
    __syncthreads();
    if (t < 256) sscan[t] = x + y;
    __syncthreads();
  }
  int gbase = rb + nodeBase;
  if (t < nin) {
    int ex = sscan[t] - slots;
    woff[t] = ex;
    offs[nodeBase + t] = gbase + ex;
    deg[nodeBase + t] = slots - 1;
    dinv[nodeBase + t] = rsqrtf((float)slots);
  }
  __syncthreads();
  int winsize = cnt + nin;
  if (winsize <= WCAP) {
    for (int i = t; i < cnt; i += 512) {
      u32 r = recs[rb + i];
      int d = r & 255u;
      u32 src = r >> 8;
      int loc = (int)atomicAdd(&cnt2[d][src / TDIV], 1u);
      stage[woff[d] + loc] = (u16)src;
    }
    if (t < nin) {
      int loc = (int)atomicAdd(&cnt2[t][(u32)(nodeBase + t) / TDIV], 1u);
      stage[woff[t] + loc] = (u16)(nodeBase + t);
    }
    __syncthreads();
    for (int i = t; i < winsize; i += 512) csr_s[gbase + i] = stage[i];
  } else {
    for (int i = t; i < cnt; i += 512) {
      u32 r = recs[rb + i];
      int d = r & 255u;
      u32 src = r >> 8;
      int loc = (int)atomicAdd(&cnt2[d][src / TDIV], 1u);
      csr_s[gbase + woff[d] + loc] = (u16)src;
    }
    if (t < nin) {
      int loc = (int)atomicAdd(&cnt2[t][(u32)(nodeBase + t) / TDIV], 1u);
      csr_s[gbase + woff[t] + loc] = (u16)(nodeBase + t);
    }
  }
}

// Prep: Vb8 = fp8(dinv[row]*V) [N,128], W1/W2 transpose+cast bf16.
__global__ void k_prep(const float* __restrict__ V, const float* __restrict__ W1,
                       const float* __restrict__ W2, const float* __restrict__ dinv,
                       u32* __restrict__ Vb8, u16* __restrict__ W1t,
                       u16* __restrict__ W2t) {
  int b = blockIdx.x;
  if (b < CAST_BLK) {
    int i = (b * 256 + threadIdx.x) * 4;
    float dv = dinv[i >> 7];
    float4 v = *(const float4*)(V + i);
    Vb8[i >> 2] = fp8x4_enc(v.x * dv, v.y * dv, v.z * dv, v.w * dv);
  } else if (b < CAST_BLK + WT1_BLK) {
    int i = (b - CAST_BLK) * 256 + threadIdx.x;
    int k = i >> 8, c = i & 255;
    W1t[c * DIN + k] = f2bf(W1[i]);
  } else {
    int i = (b - CAST_BLK - WT1_BLK) * 256 + threadIdx.x;
    int k = i >> 8, c = i & 255;
    W2t[c * DH + k] = f2bf(W2[i]);
  }
}

// Layer-1 aggregation: fp8 rows [N,128] (128 B), 8-lane groups x 16 B ->
// 8 edges per wave-instruction, depth-3 pipeline. bf16 out (dinv[node] folded).
__global__ __launch_bounds__(256) void k_agg1(const u8* __restrict__ in,
    const int* __restrict__ offs, const int* __restrict__ deg,
    const u16* __restrict__ csr_s, const float* __restrict__ dinv,
    u16* __restrict__ out) {
  int node = (blockIdx.x * 256 + threadIdx.x) >> 6;
  int lane = threadIdx.x & 63;
  if (node >= NN) return;
  int beg = offs[node];
  int end = beg + deg[node] + 1;
  float dinvn = dinv[node];
  int grp = lane >> 3, sub = lane & 7;
  float acc[16] = {};
  int e = beg + grp;
  bool v0 = e < end, v1 = e + 8 < end, v2 = e + 16 < end;
  uint4 r0, r1, r2;
  if (v0) r0 = *((const uint4*)(in + (size_t)csr_s[e] * 128) + sub);
  if (v1) r1 = *((const uint4*)(in + (size_t)csr_s[e + 8] * 128) + sub);
  if (v2) r2 = *((const uint4*)(in + (size_t)csr_s[e + 16] * 128) + sub);
  e += 24;
  while (v0) {
    bool v3 = e < end;
    uint4 r3;
    if (v3) r3 = *((const uint4*)(in + (size_t)csr_s[e] * 128) + sub);
    {
      u32 w[4] = {r0.x, r0.y, r0.z, r0.w};
#pragma unroll
      for (int j = 0; j < 4; ++j) {
        float f[4];
        fp8x4_dec(w[j], f);
        acc[4 * j + 0] += f[0];
        acc[4 * j + 1] += f[1];
        acc[4 * j + 2] += f[2];
        acc[4 * j + 3] += f[3];
      }
    }
    r0 = r1; r1 = r2; r2 = r3;
    v0 = v1; v1 = v2; v2 = v3;
    e += 8;
  }
#pragma unroll
  for (int j = 0; j < 16; ++j) {
    acc[j] += __shfl_xor(acc[j], 8, 64);
    acc[j] += __shfl_xor(acc[j], 16, 64);
    acc[j] += __shfl_xor(acc[j], 32, 64);
  }
  if (lane < 8) {
    u16* op = out + (size_t)node * 128 + sub * 16;
#pragma unroll
    for (int q = 0; q < 4; ++q) {
      ushort4 o;
      o.x = f2bf(acc[4 * q + 0] * dinvn);
      o.y = f2bf(acc[4 * q + 1] * dinvn);
      o.z = f2bf(acc[4 * q + 2] * dinvn);
      o.w = f2bf(acc[4 * q + 3] * dinvn);
      *(ushort4*)(op + 4 * q) = o;
    }
  }
}

// Layer-2 aggregation: fp8 rows [N,256], 16-lane groups, depth-3, bf16 out.
__global__ __launch_bounds__(256) void k_agg2(const u8* __restrict__ in,
    const int* __restrict__ offs, const int* __restrict__ deg,
    const u16* __restrict__ csr_s, const float* __restrict__ dinv,
    u16* __restrict__ out) {
  int node = (blockIdx.x * 256 + threadIdx.x) >> 6;
  int lane = threadIdx.x & 63;
  if (node >= NN) return;
  int beg = offs[node];
  int end = beg + deg[node] + 1;
  float dinvn = dinv[node];
  int grp = lane >> 4, sub = lane & 15;
  float acc[16] = {};
  int e = beg + grp;
  bool v0 = e < end, v1 = e + 4 < end, v2 = e + 8 < end;
  uint4 r0, r1, r2;
  if (v0) r0 = *((const uint4*)(in + (size_t)csr_s[e] * 256) + sub);
  if (v1) r1 = *((const uint4*)(in + (size_t)csr_s[e + 4] * 256) + sub);
  if (v2) r2 = *((const uint4*)(in + (size_t)csr_s[e + 8] * 256) + sub);
  e += 12;
  while (v0) {
    bool v3 = e < end;
    uint4 r3;
    if (v3) r3 = *((const uint4*)(in + (size_t)csr_s[e] * 256) + sub);
    {
      u32 w[4] = {r0.x, r0.y, r0.z, r0.w};
#pragma unroll
      for (int j = 0; j < 4; ++j) {
        float f[4];
        fp8x4_dec(w[j], f);
        acc[4 * j + 0] += f[0];
        acc[4 * j + 1] += f[1];
        acc[4 * j + 2] += f[2];
        acc[4 * j + 3] += f[3];
      }
    }
    r0 = r1; r1 = r2; r2 = r3;
    v0 = v1; v1 = v2; v2 = v3;
    e += 4;
  }
#pragma unroll
  for (int j = 0; j < 16; ++j) {
    acc[j] += __shfl_xor(acc[j], 16, 64);
    acc[j] += __shfl_xor(acc[j], 32, 64);
  }
  if (lane < 16) {
    u16* op = out + (size_t)node * 256 + sub * 16;
#pragma unroll
    for (int q = 0; q < 4; ++q) {
      ushort4 o;
      o.x = f2bf(acc[4 * q + 0] * dinvn);
      o.y = f2bf(acc[4 * q + 1] * dinvn);
      o.z = f2bf(acc[4 * q + 2] * dinvn);
      o.w = f2bf(acc[4 * q + 3] * dinvn);
      *(ushort4*)(op + 4 * q) = o;
    }
  }
}

__global__ __launch_bounds__(256) void k_mgemm(const u16* __restrict__ A,
    const u16* __restrict__ Bt, const float* __restrict__ bias,
    u16* __restrict__ out, int M, int K,
    float* __restrict__ sums, float* __restrict__ sumsq) {
  __shared__ __align__(16) u16 As[128 * 32];
  __shared__ __align__(16) u16 Bs[128 * 32];
  int t = threadIdx.x;
  int l = t & 63;
  int w = t >> 6;
  int rowBase = blockIdx.x * 128;
  int colBase = blockIdx.y * 128;
  int wr = (w >> 1) * 64, wc = (w & 1) * 64;
  int rsel = l & 15, ksel = (l >> 4) * 8;

  f32x4 acc[4][4];
#pragma unroll
  for (int mi = 0; mi < 4; ++mi)
#pragma unroll
    for (int ni = 0; ni < 4; ++ni) acc[mi][ni] = (f32x4){0.f, 0.f, 0.f, 0.f};

  for (int k0 = 0; k0 < K; k0 += 32) {
#pragma unroll
    for (int c = 0; c < 2; ++c) {
      int idx = c * 256 + t;
      int row = idx >> 2;
      int kq = idx & 3;
      const u16* ga = A + (size_t)(rowBase + row) * K + k0 + kq * 8;
      const u16* gb = Bt + (size_t)(colBase + row) * K + k0 + kq * 8;
      __builtin_amdgcn_global_load_lds(
          (const __attribute__((address_space(1))) void*)ga,
          (__attribute__((address_space(3))) void*)(&As[idx * 8]), 16, 0, 0);
      __builtin_amdgcn_global_load_lds(
          (const __attribute__((address_space(1))) void*)gb,
          (__attribute__((address_space(3))) void*)(&Bs[idx * 8]), 16, 0, 0);
    }
    __syncthreads();
    short8 a[4], b[4];
#pragma unroll
    for (int mi = 0; mi < 4; ++mi)
      a[mi] = *(const short8*)(&As[(wr + mi * 16 + rsel) * 32 + ksel]);
#pragma unroll
    for (int ni = 0; ni < 4; ++ni)
      b[ni] = *(const short8*)(&Bs[(wc + ni * 16 + rsel) * 32 + ksel]);
#pragma unroll
    for (int mi = 0; mi < 4; ++mi)
#pragma unroll
      for (int ni = 0; ni < 4; ++ni)
        acc[mi][ni] = __builtin_amdgcn_mfma_f32_16x16x32_bf16(a[mi], b[ni], acc[mi][ni], 0, 0, 0);
    __syncthreads();
  }

#pragma unroll
  for (int ni = 0; ni < 4; ++ni) {
    int col = colBase + wc + ni * 16 + (l & 15);
    float bcol = bias[col];
    float s1 = 0.f, s2 = 0.f;
#pragma unroll
    for (int mi = 0; mi < 4; ++mi) {
#pragma unroll
      for (int r = 0; r < 4; ++r) {
        int row = rowBase + wr + mi * 16 + (l >> 4) * 4 + r;
        if (row < M) {
          float v = acc[mi][ni][r] + bcol;
          s1 += v; s2 += v * v;
          out[(size_t)row * 256 + col] = f2bf(v);
        }
      }
    }
    s1 += __shfl_xor(s1, 16, 64); s1 += __shfl_xor(s1, 32, 64);
    s2 += __shfl_xor(s2, 16, 64); s2 += __shfl_xor(s2, 32, 64);
    if (l < 16) {
      atomicAdd(&sums[col], s1);
      atomicAdd(&sumsq[col], s2);
    }
  }
}

__global__ void k_scale(const float* __restrict__ sum, const float* __restrict__ sumsq,
                        const float* __restrict__ g, const float* __restrict__ be,
                        float* __restrict__ scale, float* __restrict__ shift) {
  int c = threadIdx.x;
  float mean = sum[c] / (float)NN;
  float var = sumsq[c] / (float)NN - mean * mean;
  float sc = g[c] * rsqrtf(var + BN_EPS);
  scale[c] = sc;
  shift[c] = be[c] - mean * sc;
}

// h1n8 = fp8( relu(h*scl+sft) * dinv[row] )
__global__ __launch_bounds__(256) void k_normcast(const u16* __restrict__ h,
    const float* __restrict__ scale, const float* __restrict__ shift,
    const float* __restrict__ dinv, u32* __restrict__ y) {
  long long i = ((long long)blockIdx.x * 256 + threadIdx.x) * 8;
  int row = (int)(i >> 8);
  float dv = dinv[row];
  int c = (int)(i & 255);
  ushort4 v0 = *(const ushort4*)(h + i);
  ushort4 v1 = *(const ushort4*)(h + i + 4);
  float f[8];
  f[0] = fmaxf(bf2f(v0.x) * scale[c + 0] + shift[c + 0], 0.f) * dv;
  f[1] = fmaxf(bf2f(v0.y) * scale[c + 1] + shift[c + 1], 0.f) * dv;
  f[2] = fmaxf(bf2f(v0.z) * scale[c + 2] + shift[c + 2], 0.f) * dv;
  f[3] = fmaxf(bf2f(v0.w) * scale[c + 3] + shift[c + 3], 0.f) * dv;
  f[4] = fmaxf(bf2f(v1.x) * scale[c + 4] + shift[c + 4], 0.f) * dv;
  f[5] = fmaxf(bf2f(v1.y) * scale[c + 5] + shift[c + 5], 0.f) * dv;
  f[6] = fmaxf(bf2f(v1.z) * scale[c + 6] + shift[c + 6], 0.f) * dv;
  f[7] = fmaxf(bf2f(v1.w) * scale[c + 7] + shift[c + 7], 0.f) * dv;
  uint2 o;
  o.x = fp8x4_enc(f[0], f[1], f[2], f[3]);
  o.y = fp8x4_enc(f[4], f[5], f[6], f[7]);
  *(uint2*)(y + (i >> 2)) = o;
}

__global__ __launch_bounds__(256) void k_pool(const u16* __restrict__ h,
    const float* __restrict__ scale, const float* __restrict__ shift,
    const void* batch, float* __restrict__ Gsum, int* __restrict__ Gcnt,
    const int* flag) {
  int is64 = *flag;
  int c = threadIdx.x;
  int nodeBase = blockIdx.x * 64;
  float sc = scale[c], sh = shift[c];
  float local = 0.f;
  int cur = -1, len = 0;
  int nmax = min(64, NN - nodeBase);
  for (int r = 0; r < nmax; ++r) {
    int node = nodeBase + r;
    int b = load_idx(batch, node, is64);
    if (b != cur) {
      if (cur >= 0) {
        atomicAdd(&Gsum[(size_t)cur * 256 + c], local);
        if (c == 0) atomicAdd(&Gcnt[cur], len);
      }
      cur = b; local = 0.f; len = 0;
    }
    float v = bf2f(h[(size_t)node * 256 + c]) * sc + sh;
    local += fmaxf(v, 0.f);
    len++;
  }
  if (cur >= 0) {
    atomicAdd(&Gsum[(size_t)cur * 256 + c], local);
    if (c == 0) atomicAdd(&Gcnt[cur], len);
  }
}

__global__ __launch_bounds__(128) void k_fc(const float* __restrict__ Gsum,
    const int* __restrict__ Gcnt, const float* __restrict__ Wfc,
    const float* __restrict__ bfc, float* __restrict__ out) {
  int g = blockIdx.x, j = threadIdx.x;
  float inv = 1.0f / fmaxf((float)Gcnt[g], 1.0f);
  float acc = 0.f;
#pragma unroll 4
  for (int c = 0; c < 256; ++c) acc += Gsum[(size_t)g * 256 + c] * Wfc[c * 128 + j];
  out[(size_t)g * 128 + j] = acc * inv + bfc[j];
}

extern "C" void kernel_launch(void* const* d_in, const int* in_sizes, int n_in,
                              void* d_out, int out_size, void* d_ws, size_t ws_size,
                              hipStream_t stream) {
  const float* V   = (const float*)d_in[0];
  const void*  EI  = d_in[1];
  const void*  BAT = d_in[2];
  const float* W1  = (const float*)d_in[3];
  const float* b1  = (const float*)d_in[4];
  const float* g1  = (const float*)d_in[5];
  const float* be1 = (const float*)d_in[6];
  const float* W2  = (const float*)d_in[7];
  const float* b2  = (const float*)d_in[8];
  const float* g2  = (const float*)d_in[9];
  const float* be2 = (const float*)d_in[10];
  const float* Wfc = (const float*)d_in[11];
  const float* bfc = (const float*)d_in[12];
  float* out = (float*)d_out;
  const int E  = in_sizes[1] / 2;
  const int NE = E + NN;

  char* w = (char*)d_ws;
  size_t o = 0;
  auto alloc = [&](size_t bytes) -> char* {
    char* r = w + o;
    o = (o + bytes + 255) & ~(size_t)255;
    return r;
  };
  int*   flag   = (int*)alloc(4);
  int*   deg    = (int*)alloc((size_t)NN * 4);
  int*   offs   = (int*)alloc((size_t)NN * 4);
  int*   bcnt   = (int*)alloc(NB * 4);
  int*   bbase  = (int*)alloc(NB * 4);
  int*   bcur   = (int*)alloc(NB * 4);
  u32*   recs   = (u32*)alloc((size_t)E * 4);
  u16*   csr_s  = (u16*)alloc((size_t)NE * 2);
  float* dinv   = (float*)alloc((size_t)NN * 4);
  float* stats  = (float*)alloc(8 * 256 * 4);
  float *sums1 = stats, *sumsq1 = stats + 256, *sums2 = stats + 512, *sumsq2 = stats + 768;
  float *scale1 = stats + 1024, *shift1 = stats + 1280, *scale2 = stats + 1536, *shift2 = stats + 1792;
  float* Gsum   = (float*)alloc((size_t)NG * DH * 4);
  int*   Gcnt   = (int*)alloc(NG * 4);
  u16*   W1t    = (u16*)alloc((size_t)256 * DIN * 2);
  u16*   W2t    = (u16*)alloc((size_t)256 * DH * 2);
  u32*   Vb8    = (u32*)alloc((size_t)NN * DIN);      // fp8 [N,128]
  u16*   agg1   = (u16*)alloc((size_t)NPAD * DIN * 2);
  u16*   h1b    = (u16*)alloc((size_t)NN * DH * 2);
  u32*   h1n8   = (u32*)alloc((size_t)NN * DH);       // fp8 [N,256]
  u16*   agg2   = (u16*)alloc((size_t)NPAD * DH * 2);
  u16*   h2b    = (u16*)alloc((size_t)NN * DH * 2);
  (void)n_in; (void)out_size; (void)ws_size;

  hipMemsetAsync(bcnt, 0, NB * 4, stream);
  hipMemsetAsync(stats, 0, 4 * 256 * 4, stream);
  hipMemsetAsync(Gsum, 0, (size_t)NG * DH * 4, stream);
  hipMemsetAsync(Gcnt, 0, (size_t)NG * 4, stream);

  const int gB = (E + EPB - 1) / EPB;

  k_detect<<<1, 64, 0, stream>>>((const int*)EI, flag);
  k_bcnt<<<gB, 256, 0, stream>>>(EI, E, bcnt, flag);
  k_bscan<<<1, 256, 0, stream>>>(bcnt, bbase, bcur);
  k_bfill<<<gB, 256, 0, stream>>>(EI, E, bcur, recs, flag);
  k_build<<<NB, 512, 0, stream>>>(recs, bbase, bcnt, deg, offs, dinv, csr_s);
  k_prep<<<CAST_BLK + WT1_BLK + WT2_BLK, 256, 0, stream>>>(V, W1, W2, dinv, Vb8, W1t, W2t);

  k_agg1<<<(NN + 3) / 4, 256, 0, stream>>>((const u8*)Vb8, offs, deg, csr_s, dinv, agg1);
  k_mgemm<<<dim3((NN + 127) / 128, 2), 256, 0, stream>>>(agg1, W1t, b1, h1b, NN, DIN,
                                                         sums1, sumsq1);
  k_scale<<<1, 256, 0, stream>>>(sums1, sumsq1, g1, be1, scale1, shift1);
  k_normcast<<<6250, 256, 0, stream>>>(h1b, scale1, shift1, dinv, h1n8);

  k_agg2<<<(NN + 3) / 4, 256, 0, stream>>>((const u8*)h1n8, offs, deg, csr_s, dinv, agg2);
  k_mgemm<<<dim3((NN + 127) / 128, 2), 256, 0, stream>>>(agg2, W2t, b2, h2b, NN, DH,
                                                         sums2, sumsq2);
  k_scale<<<1, 256, 0, stream>>>(sums2, sumsq2, g2, be2, scale2, shift2);

  k_pool<<<(NN + 63) / 64, 256, 0, stream>>>(h2b, scale2, shift2, BAT, Gsum, Gcnt, flag);
  k_fc<<<NG, 128, 0, stream>>>(Gsum, Gcnt, Wfc, bfc, out);
}